// Round 5
// baseline (1352.517 us; speedup 1.0000x reference)
//
#include <hip/hip_runtime.h>
#include <math.h>

typedef unsigned long long u64;
typedef unsigned int u32;

#define BB 8
#define NN 4096
#define MAXK 16
#define BQ 64          // one wave per block
#define BUFSLOTS 16    // per-lane LDS append buffer (8 KB/block)

// spatial grid
#define NC 24
#define NC2 (NC * NC)
#define NCELLS (NC * NC * NC)
#define GORIG (-4.2f)
#define GW 0.35f
#define GINVW (1.0f / GW)
// Pruning margin: covers |d2_fp - d2_true| (<= ~1.2e-4 for |coord|<=4.5) with 16x slack.
#define MARGIN 2.0e-3f

// ---- ws layout (byte offsets; total ~2.03 MiB) ----
#define OFF_TAB   0                              // float4[BB*NN]  (2x,2y,2z,sq)
#define OFF_HIST  (OFF_TAB + BB * NN * 16)       // u32[BB*NCELLS] cell counts
#define OFF_ROW   (OFF_HIST + BB * NCELLS * 4)   // u32[BB*NC2]    row counts (cz,cy)
#define OFF_START (OFF_ROW + BB * NC2 * 4)       // u32[BB*NCELLS] cell start
#define OFF_CUR   (OFF_START + BB * NCELLS * 4)  // u32[BB*NCELLS] scatter cursor
#define OFF_IDS   (OFF_CUR + BB * NCELLS * 4)    // u32[BB*NN]     per-point cell id
#define OFF_SORG  (OFF_IDS + BB * NN * 4)        // u32[BB*NN]     sorted->orig idx
#define WS_NEED   (OFF_SORG + BB * NN * 4)

// ---- branch-free in-register top-16 machinery (u64 keys, ascending) ----

__device__ __forceinline__ void bitonic16(u64 v[MAXK]) {
#pragma unroll
    for (int k = 2; k <= 16; k <<= 1) {
#pragma unroll
        for (int j = k >> 1; j > 0; j >>= 1) {
#pragma unroll
            for (int i = 0; i < 16; ++i) {
                const int l = i ^ j;
                if (l > i) {
                    const u64 a = v[i], b = v[l];
                    const bool up = ((i & k) == 0);
                    const bool sw = up ? (a > b) : (a < b);
                    v[i] = sw ? b : a;
                    v[l] = sw ? a : b;
                }
            }
        }
    }
}

__device__ __forceinline__ void merge16(u64 list[MAXK], const u64 br[MAXK]) {
    u64 lo[MAXK];
#pragma unroll
    for (int i = 0; i < 16; ++i) {
        const u64 a = list[i], b = br[15 - i];
        lo[i] = a < b ? a : b;
    }
#pragma unroll
    for (int j = 8; j > 0; j >>= 1) {
#pragma unroll
        for (int i = 0; i < 16; ++i) {
            const int l = i ^ j;
            if (l > i) {
                const u64 a = lo[i], b = lo[l];
                const bool sw = a > b;
                lo[i] = sw ? b : a;
                lo[l] = sw ? a : b;
            }
        }
    }
#pragma unroll
    for (int i = 0; i < 16; ++i) list[i] = lo[i];
}

__device__ __forceinline__ void flush_buf(u64 list[MAXK], u64& wkey, int& cnt,
                                          const u64 (*buf)[BQ], int lane) {
    u64 br[MAXK];
#pragma unroll
    for (int i = 0; i < 16; ++i) {
        const u64 v = buf[i][lane];
        br[i] = (i < cnt) ? v : ~0ull;
    }
    bitonic16(br);
    merge16(list, br);
    wkey = list[15];
    cnt = 0;
}

// k = argmax(kvec)+1 (first index wins), gather preds of selected, mean.
__device__ __forceinline__ void write_mean(const float* __restrict__ pb,
                                           const float* __restrict__ kvec,
                                           const u64 list[MAXK],
                                           float* __restrict__ op) {
    float bv = kvec[0]; int bi = 0;
#pragma unroll
    for (int i = 1; i < MAXK; ++i) { const float v = kvec[i]; if (v > bv) { bv = v; bi = i; } }
    const int k = bi + 1;
    float sx = 0.f, sy = 0.f, sz = 0.f;
#pragma unroll
    for (int s = 0; s < MAXK; ++s) {
        if (s < k) {
            const int j = (int)(u32)list[s];
            sx = __fadd_rn(sx, pb[j * 3 + 0]);
            sy = __fadd_rn(sy, pb[j * 3 + 1]);
            sz = __fadd_rn(sz, pb[j * 3 + 2]);
        }
    }
    const float fk = (float)k;
    op[0] = __fdiv_rn(sx, fk);
    op[1] = __fdiv_rn(sy, fk);
    op[2] = __fdiv_rn(sz, fk);
}

// ---- build kernels ----

__global__ __launch_bounds__(256) void knn_zero(u32* __restrict__ p, int n) {
    const int i = blockIdx.x * 256 + (int)threadIdx.x;
    if (i < n) p[i] = 0u;
}

// Per point: cell id (serpentine order), histogram + row histogram.
__global__ __launch_bounds__(256) void knn_build(const float* __restrict__ x,
                                                 u32* __restrict__ hist,
                                                 u32* __restrict__ rowcnt,
                                                 u32* __restrict__ ids) {
    const int g = blockIdx.x * 256 + (int)threadIdx.x;   // 0 .. BB*NN-1
    const int b = g >> 12;
    const float px = x[(size_t)g * 3 + 0];
    const float py = x[(size_t)g * 3 + 1];
    const float pz = x[(size_t)g * 3 + 2];
    int cx = (int)floorf((px - GORIG) * GINVW); cx = cx < 0 ? 0 : (cx > NC - 1 ? NC - 1 : cx);
    int cy = (int)floorf((py - GORIG) * GINVW); cy = cy < 0 ? 0 : (cy > NC - 1 ? NC - 1 : cy);
    int cz = (int)floorf((pz - GORIG) * GINVW); cz = cz < 0 ? 0 : (cz > NC - 1 ? NC - 1 : cz);
    const int iy = (cz & 1) ? (NC - 1 - cy) : cy;
    const int ix = ((cy + cz) & 1) ? (NC - 1 - cx) : cx;
    const int id = (cz * NC + iy) * NC + ix;             // serpentine: adjacent ids adjacent cells
    ids[g] = (u32)id;
    atomicAdd(&hist[b * NCELLS + id], 1u);
    atomicAdd(&rowcnt[(b * NC + cz) * NC + cy], 1u);
}

// Exclusive prefix sum per batch over NCELLS counters -> start & cursor.
__global__ __launch_bounds__(1024) void knn_prefix(const u32* __restrict__ hist,
                                                   u32* __restrict__ start,
                                                   u32* __restrict__ cursor) {
    const int b = blockIdx.x;
    const int tid = (int)threadIdx.x;
    const int lane = tid & 63, wid = tid >> 6;
    __shared__ u32 wsum[16];
    u32 carry = 0;
    for (int c0 = 0; c0 < NCELLS; c0 += 1024) {
        const int idx = c0 + tid;
        const u32 v = (idx < NCELLS) ? hist[b * NCELLS + idx] : 0u;
        u32 inc = v;
#pragma unroll
        for (int off = 1; off < 64; off <<= 1) {
            const u32 n = __shfl_up(inc, off);
            if (lane >= off) inc += n;
        }
        if (lane == 63) wsum[wid] = inc;
        __syncthreads();
        if (wid == 0) {
            u32 s = (lane < 16) ? wsum[lane] : 0u;
#pragma unroll
            for (int off = 1; off < 16; off <<= 1) {
                const u32 n = __shfl_up(s, off);
                if (lane >= off) s += n;
            }
            if (lane < 16) wsum[lane] = s;
        }
        __syncthreads();
        const u32 woff = wid ? wsum[wid - 1] : 0u;
        const u32 excl = carry + woff + (inc - v);
        if (idx < NCELLS) { start[b * NCELLS + idx] = excl; cursor[b * NCELLS + idx] = excl; }
        const u32 tot = wsum[15];
        __syncthreads();
        carry += tot;
    }
}

// Scatter points into cell-sorted order with (2x,2y,2z,sq) payload + orig idx.
__global__ __launch_bounds__(256) void knn_scatter(const float* __restrict__ x,
                                                   const u32* __restrict__ ids,
                                                   u32* __restrict__ cursor,
                                                   float4* __restrict__ tab,
                                                   u32* __restrict__ sorg) {
    const int g = blockIdx.x * 256 + (int)threadIdx.x;
    const int b = g >> 12, i = g & (NN - 1);
    const u32 id = ids[g];
    const u32 p = atomicAdd(&cursor[b * NCELLS + id], 1u);
    const float cx = x[(size_t)g * 3 + 0];
    const float cy = x[(size_t)g * 3 + 1];
    const float cz = x[(size_t)g * 3 + 2];
    // sq in reference fp32 op order; doubled coords are exact.
    const float sq = __fadd_rn(__fadd_rn(__fmul_rn(cx, cx), __fmul_rn(cy, cy)),
                               __fmul_rn(cz, cz));
    tab[(size_t)b * NN + p] = make_float4(__fadd_rn(cx, cx), __fadd_rn(cy, cy),
                                          __fadd_rn(cz, cz), sq);
    sorg[(size_t)b * NN + p] = (u32)i;
}

// ---- main grid-pruned scan: one wave = 64 spatially-adjacent queries ----

#define FASTPATH(C, CO) do {                                                  \
    const float inner2_ = __fadd_rn(                                          \
        __fadd_rn(__fmul_rn(qx, (C).x), __fmul_rn(qy, (C).y)),                \
        __fmul_rn(qz, (C).z));                                                \
    float d2_ = __fsub_rn(__fadd_rn(qsq, (C).w), inner2_);                    \
    d2_ = fmaxf(d2_, 0.0f);                                                   \
    const u64 key_ = ((u64)__float_as_uint(d2_) << 32) | (u64)(CO);           \
    buf[cnt][lane] = key_;                                                    \
    cnt += (key_ < wkey) ? 1 : 0;                                             \
} while (0)

__global__ __launch_bounds__(BQ) void knn_grid(
    const float* __restrict__ preds, const float* __restrict__ kvec,
    const float4* __restrict__ tab, const u32* __restrict__ sorg,
    const u32* __restrict__ hist, const u32* __restrict__ rowcnt,
    const u32* __restrict__ start, float* __restrict__ out)
{
    const int lane = (int)threadIdx.x;
    const int b = blockIdx.x >> 6;
    const int wbegin = (blockIdx.x & 63) * BQ;       // within-batch sorted slot base
    const float4* tb = tab + (size_t)b * NN;
    const u32* sg = sorg + (size_t)b * NN;

    const float4 qv = tb[wbegin + lane];             // (2x,2y,2z,sq)
    const float qx = __fmul_rn(0.5f, qv.x);          // exact
    const float qy = __fmul_rn(0.5f, qv.y);
    const float qz = __fmul_rn(0.5f, qv.z);
    const float qsq = qv.w;
    const u32 qorig = sg[wbegin + lane];

    // wave bounding box of query coords
    float bxlo = qx, bxhi = qx, bylo = qy, byhi = qy, bzlo = qz, bzhi = qz;
#pragma unroll
    for (int off = 32; off; off >>= 1) {
        bxlo = fminf(bxlo, __shfl_xor(bxlo, off)); bxhi = fmaxf(bxhi, __shfl_xor(bxhi, off));
        bylo = fminf(bylo, __shfl_xor(bylo, off)); byhi = fmaxf(byhi, __shfl_xor(byhi, off));
        bzlo = fminf(bzlo, __shfl_xor(bzlo, off)); bzhi = fmaxf(bzhi, __shfl_xor(bzhi, off));
    }

    __shared__ u64 buf[BUFSLOTS][BQ];   // [slot][lane] -> 2-way banks (free)

    u64 list[MAXK];
#pragma unroll
    for (int s = 0; s < MAXK; ++s) list[s] = ~0ull;
    u64 wkey = ~0ull;
    int cnt = 0;

    // Phase A: the wave's own 64 points (includes self, d2 == 0 exactly).
#pragma unroll 1
    for (int t = 0; t < BQ; ++t) {
        if ((t & 7) == 0 && __any((int)(cnt > BUFSLOTS - 8)))
            flush_buf(list, wkey, cnt, buf, lane);
        const float4 c = tb[wbegin + t];
        const u32 co = sg[wbegin + t];
        FASTPATH(c, co);
    }
    flush_buf(list, wkey, cnt, buf, lane);

    // Conservative scan radius: max over lanes of current 16th d2, + margin.
    float r2 = __uint_as_float((u32)(wkey >> 32));
#pragma unroll
    for (int off = 32; off; off >>= 1) r2 = fmaxf(r2, __shfl_xor(r2, off));
    r2 = __fadd_rn(r2, MARGIN);
    const float r = sqrtf(r2);

    int cxlo = (int)floorf((bxlo - r - GORIG) * GINVW);
    int cxhi = (int)floorf((bxhi + r - GORIG) * GINVW);
    int cylo = (int)floorf((bylo - r - GORIG) * GINVW);
    int cyhi = (int)floorf((byhi + r - GORIG) * GINVW);
    int czlo = (int)floorf((bzlo - r - GORIG) * GINVW);
    int czhi = (int)floorf((bzhi + r - GORIG) * GINVW);
    cxlo = cxlo < 0 ? 0 : cxlo; cxhi = cxhi > NC - 1 ? NC - 1 : cxhi;
    cylo = cylo < 0 ? 0 : cylo; cyhi = cyhi > NC - 1 ? NC - 1 : cyhi;
    czlo = czlo < 0 ? 0 : czlo; czhi = czhi > NC - 1 ? NC - 1 : czhi;
    cxlo = __builtin_amdgcn_readfirstlane(cxlo); cxhi = __builtin_amdgcn_readfirstlane(cxhi);
    cylo = __builtin_amdgcn_readfirstlane(cylo); cyhi = __builtin_amdgcn_readfirstlane(cyhi);
    czlo = __builtin_amdgcn_readfirstlane(czlo); czhi = __builtin_amdgcn_readfirstlane(czhi);

    // Phase B: all cells with mindist^2(cell AABB, box) <= r2, minus own range.
    // Border cells get open-ended AABBs (clamped outliers stay safe).
#pragma unroll 1
    for (int cz = czlo; cz <= czhi; ++cz) {
        float zlo = GORIG + cz * GW, zhi = zlo + GW;
        if (cz == 0) zlo = -1e30f;
        if (cz == NC - 1) zhi = 1e30f;
        const float dz = fmaxf(fmaxf(zlo - bzhi, bzlo - zhi), 0.0f);
        const float dz2 = dz * dz;
        if (dz2 > r2) continue;
#pragma unroll 1
        for (int cy = cylo; cy <= cyhi; ++cy) {
            const u32 rc = rowcnt[(b * NC + cz) * NC + cy];
            if (rc == 0u) continue;
            float ylo = GORIG + cy * GW, yhi = ylo + GW;
            if (cy == 0) ylo = -1e30f;
            if (cy == NC - 1) yhi = 1e30f;
            const float dy = fmaxf(fmaxf(ylo - byhi, bylo - yhi), 0.0f);
            const float dyz2 = dz2 + dy * dy;
            if (dyz2 > r2) continue;
            const int iy = (cz & 1) ? (NC - 1 - cy) : cy;
            const int flip = (cy + cz) & 1;
            const int rowid = (cz * NC + iy) * NC;
#pragma unroll 1
            for (int cx = cxlo; cx <= cxhi; ++cx) {
                float xlo = GORIG + cx * GW, xhi = xlo + GW;
                if (cx == 0) xlo = -1e30f;
                if (cx == NC - 1) xhi = 1e30f;
                const float dx = fmaxf(fmaxf(xlo - bxhi, bxlo - xhi), 0.0f);
                if (dyz2 + dx * dx > r2) continue;
                const int id = rowid + (flip ? (NC - 1 - cx) : cx);
                const u32 st = start[b * NCELLS + id];
                const u32 cn = hist[b * NCELLS + id];
                if (cn == 0u) continue;
#pragma unroll 1
                for (u32 o = 0; o < cn; o += 4) {
                    if (__any((int)(cnt > BUFSLOTS - 4)))
                        flush_buf(list, wkey, cnt, buf, lane);
                    const u32 e = (o + 4u < cn) ? o + 4u : cn;
                    for (u32 ii = o; ii < e; ++ii) {
                        const int s = (int)(st + ii);
                        if (s >= wbegin && s < wbegin + BQ) continue;  // phase A did these
                        const float4 c = tb[s];
                        const u32 co = sg[s];
                        FASTPATH(c, co);
                    }
                }
            }
        }
    }
    flush_buf(list, wkey, cnt, buf, lane);

    write_mean(preds + (size_t)b * NN * 3, kvec, list,
               out + ((size_t)b * NN + qorig) * 3);
}

// ---- fallback: fused brute force (no workspace), known-good structure ----
__global__ __launch_bounds__(BQ) void knn_brute(
    const float* __restrict__ x, const float* __restrict__ preds,
    const float* __restrict__ kvec, float* __restrict__ out)
{
    const int lane = (int)threadIdx.x;
    const int qg = blockIdx.x % (NN / BQ);
    const int b  = blockIdx.x / (NN / BQ);
    const int qi = qg * BQ + lane;
    const float* xb = x + (size_t)b * NN * 3;
    const float qx = xb[qi * 3 + 0], qy = xb[qi * 3 + 1], qz = xb[qi * 3 + 2];
    const float qsq = __fadd_rn(__fadd_rn(__fmul_rn(qx, qx), __fmul_rn(qy, qy)),
                                __fmul_rn(qz, qz));
    __shared__ u64 buf[BUFSLOTS][BQ];
    u64 list[MAXK];
#pragma unroll
    for (int s = 0; s < MAXK; ++s) list[s] = ~0ull;
    u64 wkey = ~0ull;
    int cnt = 0;
#pragma unroll 1
    for (int t = 0; t < NN; t += 4) {
        if (__any((int)(cnt > BUFSLOTS - 4))) flush_buf(list, wkey, cnt, buf, lane);
#pragma unroll
        for (int u = 0; u < 4; ++u) {
            const int j = t + u;
            const float cx = xb[j * 3 + 0], cy = xb[j * 3 + 1], cz = xb[j * 3 + 2];
            const float csq = __fadd_rn(__fadd_rn(__fmul_rn(cx, cx), __fmul_rn(cy, cy)),
                                        __fmul_rn(cz, cz));
            const float inner = __fadd_rn(
                __fadd_rn(__fmul_rn(qx, cx), __fmul_rn(qy, cy)), __fmul_rn(qz, cz));
            float d2 = __fsub_rn(__fadd_rn(qsq, csq), __fmul_rn(2.0f, inner));
            d2 = fmaxf(d2, 0.0f);
            const u64 key = ((u64)__float_as_uint(d2) << 32) | (u32)j;
            buf[cnt][lane] = key;
            cnt += (key < wkey) ? 1 : 0;
        }
    }
    flush_buf(list, wkey, cnt, buf, lane);
    write_mean(preds + (size_t)b * NN * 3, kvec, list,
               out + ((size_t)b * NN + qi) * 3);
}

extern "C" void kernel_launch(void* const* d_in, const int* in_sizes, int n_in,
                              void* d_out, int out_size, void* d_ws, size_t ws_size,
                              hipStream_t stream) {
    (void)in_sizes; (void)n_in; (void)out_size;
    const float* x     = (const float*)d_in[0];
    const float* preds = (const float*)d_in[1];
    const float* kvec  = (const float*)d_in[2];
    float* out = (float*)d_out;

    if (ws_size >= (size_t)WS_NEED) {
        char* w = (char*)d_ws;
        float4* tab  = (float4*)(w + OFF_TAB);
        u32* hist    = (u32*)(w + OFF_HIST);
        u32* rowcnt  = (u32*)(w + OFF_ROW);
        u32* startp  = (u32*)(w + OFF_START);
        u32* cursor  = (u32*)(w + OFF_CUR);
        u32* ids     = (u32*)(w + OFF_IDS);
        u32* sorg    = (u32*)(w + OFF_SORG);

        const int nz = BB * NCELLS + BB * NC2;   // hist + rowcnt are contiguous
        knn_zero<<<(nz + 255) / 256, 256, 0, stream>>>(hist, nz);
        knn_build<<<(BB * NN) / 256, 256, 0, stream>>>(x, hist, rowcnt, ids);
        knn_prefix<<<BB, 1024, 0, stream>>>(hist, startp, cursor);
        knn_scatter<<<(BB * NN) / 256, 256, 0, stream>>>(x, ids, cursor, tab, sorg);
        knn_grid<<<BB * (NN / BQ), BQ, 0, stream>>>(preds, kvec, tab, sorg,
                                                    hist, rowcnt, startp, out);
    } else {
        knn_brute<<<BB * (NN / BQ), BQ, 0, stream>>>(x, preds, kvec, out);
    }
}

// Round 6
// 1175.861 us; speedup vs baseline: 1.1502x; 1.1502x over previous
//
#include <hip/hip_runtime.h>
#include <math.h>

typedef unsigned long long u64;
typedef unsigned int u32;

#define BB 8
#define NN 4096
#define MAXK 16
#define BQ 64          // one wave per block
#define BUFSLOTS 16    // per-lane LDS append buffer (8 KB/block)
#define SIBS 4         // sibling blocks per query wave

// spatial grid
#define NC 24
#define NC2 (NC * NC)
#define NCM (1 << 15)  // morton cell id space (5 bits/axis)
#define GORIG (-4.2f)
#define GW 0.35f
#define GINVW (1.0f / GW)
// Pruning margin: covers |d2_fp - d2_true| (<= ~1e-5 here) with large slack.
#define MARGIN 2.0e-3f

// ---- ws layout (byte offsets; ~19.8 MiB) ----
#define OFF_TAB   0                                   // float4[BB*NN] (2x,2y,2z,sq)
#define OFF_KEYS  (OFF_TAB + BB * NN * 16)            // u64[SIBS*16][BB*NN]
#define OFF_HIST  (OFF_KEYS + SIBS * MAXK * BB * NN * 8)  // u32[BB*NCM]
#define OFF_ROW   (OFF_HIST + BB * NCM * 4)           // u32[BB*NC2]  (contig w/ hist for zeroing)
#define OFF_START (OFF_ROW + BB * NC2 * 4)            // u32[BB*NCM]
#define OFF_CUR   (OFF_START + BB * NCM * 4)          // u32[BB*NCM]
#define OFF_IDS   (OFF_CUR + BB * NCM * 4)            // u32[BB*NN] morton id per point
#define OFF_SORG  (OFF_IDS + BB * NN * 4)             // u32[BB*NN] sorted->orig
#define WS_NEED   (OFF_SORG + BB * NN * 4)

__device__ __forceinline__ u32 part1by2(u32 x) {
    x &= 0x3FF;
    x = (x | (x << 16)) & 0x030000FF;
    x = (x | (x << 8))  & 0x0300F00F;
    x = (x | (x << 4))  & 0x030C30C3;
    x = (x | (x << 2))  & 0x09249249;
    return x;
}

// ---- branch-free in-register top-16 machinery (u64 keys, ascending) ----

__device__ __forceinline__ void bitonic16(u64 v[MAXK]) {
#pragma unroll
    for (int k = 2; k <= 16; k <<= 1) {
#pragma unroll
        for (int j = k >> 1; j > 0; j >>= 1) {
#pragma unroll
            for (int i = 0; i < 16; ++i) {
                const int l = i ^ j;
                if (l > i) {
                    const u64 a = v[i], b = v[l];
                    const bool up = ((i & k) == 0);
                    const bool sw = up ? (a > b) : (a < b);
                    v[i] = sw ? b : a;
                    v[l] = sw ? a : b;
                }
            }
        }
    }
}

__device__ __forceinline__ void merge16(u64 list[MAXK], const u64 br[MAXK]) {
    u64 lo[MAXK];
#pragma unroll
    for (int i = 0; i < 16; ++i) {
        const u64 a = list[i], b = br[15 - i];
        lo[i] = a < b ? a : b;
    }
#pragma unroll
    for (int j = 8; j > 0; j >>= 1) {
#pragma unroll
        for (int i = 0; i < 16; ++i) {
            const int l = i ^ j;
            if (l > i) {
                const u64 a = lo[i], b = lo[l];
                const bool sw = a > b;
                lo[i] = sw ? b : a;
                lo[l] = sw ? a : b;
            }
        }
    }
#pragma unroll
    for (int i = 0; i < 16; ++i) list[i] = lo[i];
}

// floorv: append-filter floor (per-lane); wkey = min(list[15], floorv).
__device__ __forceinline__ void flush_buf(u64 list[MAXK], u64& wkey, int& cnt,
                                          const u64 (*buf)[BQ], int lane, u64 floorv) {
    u64 br[MAXK];
#pragma unroll
    for (int i = 0; i < 16; ++i) {
        const u64 v = buf[i][lane];
        br[i] = (i < cnt) ? v : ~0ull;
    }
    bitonic16(br);
    merge16(list, br);
    const u64 l15 = list[15];
    wkey = l15 < floorv ? l15 : floorv;
    cnt = 0;
}

// k = argmax(kvec)+1 (first index wins), gather preds of selected, mean.
__device__ __forceinline__ void write_mean(const float* __restrict__ pb,
                                           const float* __restrict__ kvec,
                                           const u64 list[MAXK],
                                           float* __restrict__ op) {
    float bv = kvec[0]; int bi = 0;
#pragma unroll
    for (int i = 1; i < MAXK; ++i) { const float v = kvec[i]; if (v > bv) { bv = v; bi = i; } }
    const int k = bi + 1;
    float sx = 0.f, sy = 0.f, sz = 0.f;
#pragma unroll
    for (int s = 0; s < MAXK; ++s) {
        if (s < k) {
            const int j = (int)(u32)list[s];
            sx = __fadd_rn(sx, pb[j * 3 + 0]);
            sy = __fadd_rn(sy, pb[j * 3 + 1]);
            sz = __fadd_rn(sz, pb[j * 3 + 2]);
        }
    }
    const float fk = (float)k;
    op[0] = __fdiv_rn(sx, fk);
    op[1] = __fdiv_rn(sy, fk);
    op[2] = __fdiv_rn(sz, fk);
}

// ---- build kernels ----

__global__ __launch_bounds__(256) void knn_zero(u32* __restrict__ p, int n) {
    const int i = blockIdx.x * 256 + (int)threadIdx.x;
    if (i < n) p[i] = 0u;
}

__global__ __launch_bounds__(256) void knn_build(const float* __restrict__ x,
                                                 u32* __restrict__ hist,
                                                 u32* __restrict__ rowcnt,
                                                 u32* __restrict__ ids) {
    const int g = blockIdx.x * 256 + (int)threadIdx.x;   // 0 .. BB*NN-1
    const int b = g >> 12;
    const float px = x[(size_t)g * 3 + 0];
    const float py = x[(size_t)g * 3 + 1];
    const float pz = x[(size_t)g * 3 + 2];
    int cx = (int)floorf((px - GORIG) * GINVW); cx = cx < 0 ? 0 : (cx > NC - 1 ? NC - 1 : cx);
    int cy = (int)floorf((py - GORIG) * GINVW); cy = cy < 0 ? 0 : (cy > NC - 1 ? NC - 1 : cy);
    int cz = (int)floorf((pz - GORIG) * GINVW); cz = cz < 0 ? 0 : (cz > NC - 1 ? NC - 1 : cz);
    const u32 m = (part1by2((u32)cz) << 2) | (part1by2((u32)cy) << 1) | part1by2((u32)cx);
    ids[g] = m;
    atomicAdd(&hist[b * NCM + (int)m], 1u);
    atomicAdd(&rowcnt[(b * NC + cz) * NC + cy], 1u);
}

__global__ __launch_bounds__(1024) void knn_prefix(const u32* __restrict__ hist,
                                                   u32* __restrict__ start,
                                                   u32* __restrict__ cursor) {
    const int b = blockIdx.x;
    const int tid = (int)threadIdx.x;
    const int lane = tid & 63, wid = tid >> 6;
    __shared__ u32 wsum[16];
    u32 carry = 0;
    for (int c0 = 0; c0 < NCM; c0 += 1024) {
        const int idx = c0 + tid;
        const u32 v = hist[b * NCM + idx];
        u32 inc = v;
#pragma unroll
        for (int off = 1; off < 64; off <<= 1) {
            const u32 n = __shfl_up(inc, off);
            if (lane >= off) inc += n;
        }
        if (lane == 63) wsum[wid] = inc;
        __syncthreads();
        if (wid == 0) {
            u32 s = (lane < 16) ? wsum[lane] : 0u;
#pragma unroll
            for (int off = 1; off < 16; off <<= 1) {
                const u32 n = __shfl_up(s, off);
                if (lane >= off) s += n;
            }
            if (lane < 16) wsum[lane] = s;
        }
        __syncthreads();
        const u32 woff = wid ? wsum[wid - 1] : 0u;
        const u32 excl = carry + woff + (inc - v);
        start[b * NCM + idx] = excl; cursor[b * NCM + idx] = excl;
        const u32 tot = wsum[15];
        __syncthreads();
        carry += tot;
    }
}

__global__ __launch_bounds__(256) void knn_scatter(const float* __restrict__ x,
                                                   const u32* __restrict__ ids,
                                                   u32* __restrict__ cursor,
                                                   float4* __restrict__ tab,
                                                   u32* __restrict__ sorg) {
    const int g = blockIdx.x * 256 + (int)threadIdx.x;
    const int b = g >> 12, i = g & (NN - 1);
    const u32 id = ids[g];
    const u32 p = atomicAdd(&cursor[b * NCM + (int)id], 1u);
    const float cx = x[(size_t)g * 3 + 0];
    const float cy = x[(size_t)g * 3 + 1];
    const float cz = x[(size_t)g * 3 + 2];
    const float sq = __fadd_rn(__fadd_rn(__fmul_rn(cx, cx), __fmul_rn(cy, cy)),
                               __fmul_rn(cz, cz));
    tab[(size_t)b * NN + p] = make_float4(__fadd_rn(cx, cx), __fadd_rn(cy, cy),
                                          __fadd_rn(cz, cz), sq);
    sorg[(size_t)b * NN + p] = (u32)i;
}

// ---- main grid-pruned scan ----

#define FASTPATH(C, CO) do {                                                  \
    const float inner2_ = __fadd_rn(                                          \
        __fadd_rn(__fmul_rn(qx, (C).x), __fmul_rn(qy, (C).y)),                \
        __fmul_rn(qz, (C).z));                                                \
    float d2_ = __fsub_rn(__fadd_rn(qsq, (C).w), inner2_);                    \
    d2_ = fmaxf(d2_, 0.0f);                                                   \
    const u64 key_ = ((u64)__float_as_uint(d2_) << 32) | (u64)(CO);           \
    buf[cnt][lane] = key_;                                                    \
    cnt += (key_ < wkey) ? 1 : 0;                                             \
} while (0)

__global__ __launch_bounds__(BQ) void knn_grid(
    const float4* __restrict__ tab, const u32* __restrict__ sorg,
    const u32* __restrict__ hist, const u32* __restrict__ rowcnt,
    const u32* __restrict__ start, u64* __restrict__ keys)
{
    const int lane = (int)threadIdx.x;
    int bid = blockIdx.x;
    const int sib = bid & (SIBS - 1); bid >>= 2;
    const int b = bid >> 6;
    const int wbegin = (bid & 63) * BQ;              // within-batch sorted slot base
    const float4* tb = tab + (size_t)b * NN;

    const float4 qv = tb[wbegin + lane];             // (2x,2y,2z,sq)
    const float qx = __fmul_rn(0.5f, qv.x);          // exact
    const float qy = __fmul_rn(0.5f, qv.y);
    const float qz = __fmul_rn(0.5f, qv.z);
    const float qsq = qv.w;

    // wave bounding box of query coords
    float bxlo = qx, bxhi = qx, bylo = qy, byhi = qy, bzlo = qz, bzhi = qz;
#pragma unroll
    for (int off = 32; off; off >>= 1) {
        bxlo = fminf(bxlo, __shfl_xor(bxlo, off)); bxhi = fmaxf(bxhi, __shfl_xor(bxhi, off));
        bylo = fminf(bylo, __shfl_xor(bylo, off)); byhi = fmaxf(byhi, __shfl_xor(byhi, off));
        bzlo = fminf(bzlo, __shfl_xor(bzlo, off)); bzhi = fmaxf(bzhi, __shfl_xor(bzhi, off));
    }

    __shared__ u64 buf[BUFSLOTS][BQ];

    u64 list[MAXK];
#pragma unroll
    for (int s = 0; s < MAXK; ++s) list[s] = ~0ull;
    u64 wkey = ~0ull;
    int cnt = 0;

    // Phase A: the wave's own 64 points (includes self). All siblings duplicate
    // this (cheap) to get the per-lane floor + r2 without communication.
    const u32* sg = sorg + (size_t)b * NN;
#pragma unroll 1
    for (int t = 0; t < BQ; t += 8) {
        if (__any((int)(cnt > BUFSLOTS - 8)))
            flush_buf(list, wkey, cnt, buf, lane, ~0ull);
#pragma unroll
        for (int u = 0; u < 8; ++u) {
            const float4 c = tb[wbegin + t + u];
            const u32 co = sg[wbegin + t + u];
            FASTPATH(c, co);
        }
    }
    flush_buf(list, wkey, cnt, buf, lane, ~0ull);

    const u64 paw = wkey;          // per-lane 16th-best bound (floor from here on)
    if (sib != 0) {
        // Avoid duplicate keys across siblings: only sib 0 keeps phase A's list.
#pragma unroll
        for (int s = 0; s < MAXK; ++s) list[s] = ~0ull;
        // wkey stays paw: appends beyond the phase-A bound can never matter.
    }

    // Conservative scan radius: max over lanes of 16th d2, + margin.
    float r2 = __uint_as_float((u32)(paw >> 32));
#pragma unroll
    for (int off = 32; off; off >>= 1) r2 = fmaxf(r2, __shfl_xor(r2, off));
    r2 = __fadd_rn(r2, MARGIN);
    const float r = sqrtf(r2);

    int cxlo = (int)floorf((bxlo - r - GORIG) * GINVW);
    int cxhi = (int)floorf((bxhi + r - GORIG) * GINVW);
    int cylo = (int)floorf((bylo - r - GORIG) * GINVW);
    int cyhi = (int)floorf((byhi + r - GORIG) * GINVW);
    int czlo = (int)floorf((bzlo - r - GORIG) * GINVW);
    int czhi = (int)floorf((bzhi + r - GORIG) * GINVW);
    cxlo = cxlo < 0 ? 0 : cxlo; cxhi = cxhi > NC - 1 ? NC - 1 : cxhi;
    cylo = cylo < 0 ? 0 : cylo; cyhi = cyhi > NC - 1 ? NC - 1 : cyhi;
    czlo = czlo < 0 ? 0 : czlo; czhi = czhi > NC - 1 ? NC - 1 : czhi;
    cxlo = __builtin_amdgcn_readfirstlane(cxlo); cxhi = __builtin_amdgcn_readfirstlane(cxhi);
    cylo = __builtin_amdgcn_readfirstlane(cylo); cyhi = __builtin_amdgcn_readfirstlane(cyhi);
    czlo = __builtin_amdgcn_readfirstlane(czlo); czhi = __builtin_amdgcn_readfirstlane(czhi);

    // Phase B: AABB-accepted cells dealt round-robin to the 4 siblings via a
    // deterministic counter (identical traversal in all siblings).
    int cellctr = 0;
#pragma unroll 1
    for (int cz = czlo; cz <= czhi; ++cz) {
        float zlo = GORIG + cz * GW, zhi = zlo + GW;
        if (cz == 0) zlo = -1e30f;
        if (cz == NC - 1) zhi = 1e30f;
        const float dz = fmaxf(fmaxf(zlo - bzhi, bzlo - zhi), 0.0f);
        const float dz2 = dz * dz;
        if (dz2 > r2) continue;
        const u32 mz = part1by2((u32)cz) << 2;
#pragma unroll 1
        for (int cy = cylo; cy <= cyhi; ++cy) {
            if (rowcnt[(b * NC + cz) * NC + cy] == 0u) continue;
            float ylo = GORIG + cy * GW, yhi = ylo + GW;
            if (cy == 0) ylo = -1e30f;
            if (cy == NC - 1) yhi = 1e30f;
            const float dy = fmaxf(fmaxf(ylo - byhi, bylo - yhi), 0.0f);
            const float dyz2 = dz2 + dy * dy;
            if (dyz2 > r2) continue;
            const u32 mzy = mz | (part1by2((u32)cy) << 1);
#pragma unroll 1
            for (int cx = cxlo; cx <= cxhi; ++cx) {
                float xlo = GORIG + cx * GW, xhi = xlo + GW;
                if (cx == 0) xlo = -1e30f;
                if (cx == NC - 1) xhi = 1e30f;
                const float dx = fmaxf(fmaxf(xlo - bxhi, bxlo - xhi), 0.0f);
                if (dyz2 + dx * dx > r2) continue;
                const bool mine = ((cellctr++) & (SIBS - 1)) == sib;
                if (!mine) continue;
                const u32 m = mzy | part1by2((u32)cx);
                const u32 cn = hist[b * NCM + (int)m];
                if (cn == 0u) continue;
                const u32 st = start[b * NCM + (int)m];
#pragma unroll 1
                for (u32 o = 0; o < cn; o += 4) {
                    if (__any((int)(cnt > BUFSLOTS - 4)))
                        flush_buf(list, wkey, cnt, buf, lane, paw);
                    const u32 e = (o + 4u < cn) ? o + 4u : cn;
                    for (u32 ii = o; ii < e; ++ii) {
                        const int s = (int)(st + ii);
                        if (s >= wbegin && s < wbegin + BQ) continue;  // phase A did these
                        const float4 c = tb[s];
                        const u32 co = sg[s];
                        FASTPATH(c, co);
                    }
                }
            }
        }
    }
    flush_buf(list, wkey, cnt, buf, lane, paw);

    // Coalesced sorted-slot-indexed key dump; merge maps sorted->orig.
    const size_t qs = (size_t)b * NN + wbegin + lane;
#pragma unroll
    for (int s = 0; s < MAXK; ++s)
        keys[(size_t)(sib * MAXK + s) * (BB * NN) + qs] = list[s];
}

__global__ __launch_bounds__(256) void knn_merge4(
    const float* __restrict__ preds, const float* __restrict__ kvec,
    const u64* __restrict__ keys, const u32* __restrict__ sorg,
    float* __restrict__ out)
{
    const int qs = blockIdx.x * 256 + (int)threadIdx.x;   // sorted slot, 0..B*N-1

    u64 list[MAXK];
#pragma unroll
    for (int s = 0; s < MAXK; ++s)
        list[s] = keys[(size_t)s * (BB * NN) + qs];        // coalesced
#pragma unroll 1
    for (int g = 1; g < SIBS; ++g) {
        u64 br[MAXK];
#pragma unroll
        for (int s = 0; s < MAXK; ++s)
            br[s] = keys[(size_t)(g * MAXK + s) * (BB * NN) + qs];
        merge16(list, br);
    }

    const int b = qs >> 12;
    const int qorig = (int)sorg[qs];
    write_mean(preds + (size_t)b * NN * 3, kvec, list,
               out + ((size_t)b * NN + qorig) * 3);
}

// ---- fallback: fused brute force (no workspace), known-good structure ----
__global__ __launch_bounds__(BQ) void knn_brute(
    const float* __restrict__ x, const float* __restrict__ preds,
    const float* __restrict__ kvec, float* __restrict__ out)
{
    const int lane = (int)threadIdx.x;
    const int qg = blockIdx.x % (NN / BQ);
    const int b  = blockIdx.x / (NN / BQ);
    const int qi = qg * BQ + lane;
    const float* xb = x + (size_t)b * NN * 3;
    const float qx = xb[qi * 3 + 0], qy = xb[qi * 3 + 1], qz = xb[qi * 3 + 2];
    const float qsq = __fadd_rn(__fadd_rn(__fmul_rn(qx, qx), __fmul_rn(qy, qy)),
                                __fmul_rn(qz, qz));
    __shared__ u64 buf[BUFSLOTS][BQ];
    u64 list[MAXK];
#pragma unroll
    for (int s = 0; s < MAXK; ++s) list[s] = ~0ull;
    u64 wkey = ~0ull;
    int cnt = 0;
#pragma unroll 1
    for (int t = 0; t < NN; t += 4) {
        if (__any((int)(cnt > BUFSLOTS - 4))) flush_buf(list, wkey, cnt, buf, lane, ~0ull);
#pragma unroll
        for (int u = 0; u < 4; ++u) {
            const int j = t + u;
            const float cx = xb[j * 3 + 0], cy = xb[j * 3 + 1], cz = xb[j * 3 + 2];
            const float csq = __fadd_rn(__fadd_rn(__fmul_rn(cx, cx), __fmul_rn(cy, cy)),
                                        __fmul_rn(cz, cz));
            const float inner = __fadd_rn(
                __fadd_rn(__fmul_rn(qx, cx), __fmul_rn(qy, cy)), __fmul_rn(qz, cz));
            float d2 = __fsub_rn(__fadd_rn(qsq, csq), __fmul_rn(2.0f, inner));
            d2 = fmaxf(d2, 0.0f);
            const u64 key = ((u64)__float_as_uint(d2) << 32) | (u32)j;
            buf[cnt][lane] = key;
            cnt += (key < wkey) ? 1 : 0;
        }
    }
    flush_buf(list, wkey, cnt, buf, lane, ~0ull);
    write_mean(preds + (size_t)b * NN * 3, kvec, list,
               out + ((size_t)b * NN + qi) * 3);
}

extern "C" void kernel_launch(void* const* d_in, const int* in_sizes, int n_in,
                              void* d_out, int out_size, void* d_ws, size_t ws_size,
                              hipStream_t stream) {
    (void)in_sizes; (void)n_in; (void)out_size;
    const float* x     = (const float*)d_in[0];
    const float* preds = (const float*)d_in[1];
    const float* kvec  = (const float*)d_in[2];
    float* out = (float*)d_out;

    if (ws_size >= (size_t)WS_NEED) {
        char* w = (char*)d_ws;
        float4* tab  = (float4*)(w + OFF_TAB);
        u64* keys    = (u64*)(w + OFF_KEYS);
        u32* hist    = (u32*)(w + OFF_HIST);
        u32* rowcnt  = (u32*)(w + OFF_ROW);
        u32* startp  = (u32*)(w + OFF_START);
        u32* cursor  = (u32*)(w + OFF_CUR);
        u32* ids     = (u32*)(w + OFF_IDS);
        u32* sorg    = (u32*)(w + OFF_SORG);

        const int nz = BB * NCM + BB * NC2;   // hist + rowcnt contiguous
        knn_zero<<<(nz + 255) / 256, 256, 0, stream>>>(hist, nz);
        knn_build<<<(BB * NN) / 256, 256, 0, stream>>>(x, hist, rowcnt, ids);
        knn_prefix<<<BB, 1024, 0, stream>>>(hist, startp, cursor);
        knn_scatter<<<(BB * NN) / 256, 256, 0, stream>>>(x, ids, cursor, tab, sorg);
        knn_grid<<<BB * (NN / BQ) * SIBS, BQ, 0, stream>>>(tab, sorg, hist, rowcnt,
                                                           startp, keys);
        knn_merge4<<<(BB * NN) / 256, 256, 0, stream>>>(preds, kvec, keys, sorg, out);
    } else {
        knn_brute<<<BB * (NN / BQ), BQ, 0, stream>>>(x, preds, kvec, out);
    }
}

// Round 7
// 461.721 us; speedup vs baseline: 2.9293x; 2.5467x over previous
//
#include <hip/hip_runtime.h>
#include <math.h>

typedef unsigned long long u64;
typedef unsigned int u32;

#define BB 8
#define NN 4096
#define MAXK 16
#define BQ 64          // one wave per block
#define BUFSLOTS 16    // per-lane LDS append buffer (8 KB/block)
#define SIBS 4         // sibling blocks per query wave

// spatial grid
#define NC 24
#define NCM (1 << 15)  // morton cell id space (5 bits/axis)
#define GORIG (-4.2f)
#define GW 0.35f
#define GINVW (1.0f / GW)
// Pruning margin: covers |d2_fp - d2_true| (<= ~2e-5) with large slack.
#define MARGIN 2.0e-3f

// ---- ws layout (byte offsets; ~20.8 MiB total) ----
#define OFF_TAB   0                                       // float4[BB*NN] (2x,2y,2z,sq)
#define OFF_KEYS  (OFF_TAB + BB * NN * 16)                // u64[SIBS*16][BB*NN]
#define OFF_DESC  (OFF_KEYS + SIBS * MAXK * BB * NN * 8)  // u64[BB*NCM] (cnt<<32)|start
#define OFF_HIST  (OFF_DESC + BB * NCM * 8)               // u32[BB*NCM]
#define OFF_CUR   (OFF_HIST + BB * NCM * 4)               // u32[BB*NCM]
#define OFF_IDS   (OFF_CUR + BB * NCM * 4)                // u32[BB*NN] morton id per point
#define OFF_SORG  (OFF_IDS + BB * NN * 4)                 // u32[BB*NN] sorted->orig
#define WS_NEED   (OFF_SORG + BB * NN * 4)

__device__ __forceinline__ u32 part1by2(u32 x) {
    x &= 0x3FF;
    x = (x | (x << 16)) & 0x030000FF;
    x = (x | (x << 8))  & 0x0300F00F;
    x = (x | (x << 4))  & 0x030C30C3;
    x = (x | (x << 2))  & 0x09249249;
    return x;
}

// ---- branch-free in-register top-16 machinery (u64 keys, ascending) ----

__device__ __forceinline__ void bitonic16(u64 v[MAXK]) {
#pragma unroll
    for (int k = 2; k <= 16; k <<= 1) {
#pragma unroll
        for (int j = k >> 1; j > 0; j >>= 1) {
#pragma unroll
            for (int i = 0; i < 16; ++i) {
                const int l = i ^ j;
                if (l > i) {
                    const u64 a = v[i], b = v[l];
                    const bool up = ((i & k) == 0);
                    const bool sw = up ? (a > b) : (a < b);
                    v[i] = sw ? b : a;
                    v[l] = sw ? a : b;
                }
            }
        }
    }
}

__device__ __forceinline__ void merge16(u64 list[MAXK], const u64 br[MAXK]) {
    u64 lo[MAXK];
#pragma unroll
    for (int i = 0; i < 16; ++i) {
        const u64 a = list[i], b = br[15 - i];
        lo[i] = a < b ? a : b;
    }
#pragma unroll
    for (int j = 8; j > 0; j >>= 1) {
#pragma unroll
        for (int i = 0; i < 16; ++i) {
            const int l = i ^ j;
            if (l > i) {
                const u64 a = lo[i], b = lo[l];
                const bool sw = a > b;
                lo[i] = sw ? b : a;
                lo[l] = sw ? a : b;
            }
        }
    }
#pragma unroll
    for (int i = 0; i < 16; ++i) list[i] = lo[i];
}

// floorv: append-filter floor (per-lane); wkey = min(list[15], floorv).
__device__ __forceinline__ void flush_buf(u64 list[MAXK], u64& wkey, int& cnt,
                                          const u64 (*buf)[BQ], int lane, u64 floorv) {
    u64 br[MAXK];
#pragma unroll
    for (int i = 0; i < 16; ++i) {
        const u64 v = buf[i][lane];
        br[i] = (i < cnt) ? v : ~0ull;
    }
    bitonic16(br);
    merge16(list, br);
    const u64 l15 = list[15];
    wkey = l15 < floorv ? l15 : floorv;
    cnt = 0;
}

// k = argmax(kvec)+1 (first index wins), gather preds of selected, mean.
__device__ __forceinline__ void write_mean(const float* __restrict__ pb,
                                           const float* __restrict__ kvec,
                                           const u64 list[MAXK],
                                           float* __restrict__ op) {
    float bv = kvec[0]; int bi = 0;
#pragma unroll
    for (int i = 1; i < MAXK; ++i) { const float v = kvec[i]; if (v > bv) { bv = v; bi = i; } }
    const int k = bi + 1;
    float sx = 0.f, sy = 0.f, sz = 0.f;
#pragma unroll
    for (int s = 0; s < MAXK; ++s) {
        if (s < k) {
            const int j = (int)(u32)list[s];
            sx = __fadd_rn(sx, pb[j * 3 + 0]);
            sy = __fadd_rn(sy, pb[j * 3 + 1]);
            sz = __fadd_rn(sz, pb[j * 3 + 2]);
        }
    }
    const float fk = (float)k;
    op[0] = __fdiv_rn(sx, fk);
    op[1] = __fdiv_rn(sy, fk);
    op[2] = __fdiv_rn(sz, fk);
}

// ---- build kernels ----

__global__ __launch_bounds__(256) void knn_zero(u32* __restrict__ p, int n) {
    const int i = blockIdx.x * 256 + (int)threadIdx.x;
    if (i < n) p[i] = 0u;
}

__global__ __launch_bounds__(256) void knn_build(const float* __restrict__ x,
                                                 u32* __restrict__ hist,
                                                 u32* __restrict__ ids) {
    const int g = blockIdx.x * 256 + (int)threadIdx.x;   // 0 .. BB*NN-1
    const int b = g >> 12;
    const float px = x[(size_t)g * 3 + 0];
    const float py = x[(size_t)g * 3 + 1];
    const float pz = x[(size_t)g * 3 + 2];
    int cx = (int)floorf((px - GORIG) * GINVW); cx = cx < 0 ? 0 : (cx > NC - 1 ? NC - 1 : cx);
    int cy = (int)floorf((py - GORIG) * GINVW); cy = cy < 0 ? 0 : (cy > NC - 1 ? NC - 1 : cy);
    int cz = (int)floorf((pz - GORIG) * GINVW); cz = cz < 0 ? 0 : (cz > NC - 1 ? NC - 1 : cz);
    const u32 m = (part1by2((u32)cz) << 2) | (part1by2((u32)cy) << 1) | part1by2((u32)cx);
    ids[g] = m;
    atomicAdd(&hist[b * NCM + (int)m], 1u);
}

// Exclusive prefix per batch; emits packed desc = (count<<32)|start and cursor.
__global__ __launch_bounds__(1024) void knn_prefix(const u32* __restrict__ hist,
                                                   u64* __restrict__ desc,
                                                   u32* __restrict__ cursor) {
    const int b = blockIdx.x;
    const int tid = (int)threadIdx.x;
    const int lane = tid & 63, wid = tid >> 6;
    __shared__ u32 wsum[16];
    u32 carry = 0;
    for (int c0 = 0; c0 < NCM; c0 += 4096) {
        const int base = b * NCM + c0 + tid * 4;
        const uint4 v = *(const uint4*)(hist + base);
        const u32 s0 = v.x, s1 = s0 + v.y, s2 = s1 + v.z, s3 = s2 + v.w;
        u32 inc = s3;
#pragma unroll
        for (int off = 1; off < 64; off <<= 1) {
            const u32 n = __shfl_up(inc, off);
            if (lane >= off) inc += n;
        }
        if (lane == 63) wsum[wid] = inc;
        __syncthreads();
        if (wid == 0) {
            u32 s = (lane < 16) ? wsum[lane] : 0u;
#pragma unroll
            for (int off = 1; off < 16; off <<= 1) {
                const u32 n = __shfl_up(s, off);
                if (lane >= off) s += n;
            }
            if (lane < 16) wsum[lane] = s;
        }
        __syncthreads();
        const u32 woff = wid ? wsum[wid - 1] : 0u;
        const u32 tot = wsum[15];
        const u32 excl = carry + woff + (inc - s3);
        const u32 st0 = excl, st1 = excl + s0, st2 = excl + s1, st3 = excl + s2;
        desc[base + 0] = ((u64)v.x << 32) | st0;
        desc[base + 1] = ((u64)v.y << 32) | st1;
        desc[base + 2] = ((u64)v.z << 32) | st2;
        desc[base + 3] = ((u64)v.w << 32) | st3;
        cursor[base + 0] = st0; cursor[base + 1] = st1;
        cursor[base + 2] = st2; cursor[base + 3] = st3;
        __syncthreads();
        carry += tot;
    }
}

__global__ __launch_bounds__(256) void knn_scatter(const float* __restrict__ x,
                                                   const u32* __restrict__ ids,
                                                   u32* __restrict__ cursor,
                                                   float4* __restrict__ tab,
                                                   u32* __restrict__ sorg) {
    const int g = blockIdx.x * 256 + (int)threadIdx.x;
    const int b = g >> 12, i = g & (NN - 1);
    const u32 id = ids[g];
    const u32 p = atomicAdd(&cursor[b * NCM + (int)id], 1u);   // batch-local slot
    const float cx = x[(size_t)g * 3 + 0];
    const float cy = x[(size_t)g * 3 + 1];
    const float cz = x[(size_t)g * 3 + 2];
    const float sq = __fadd_rn(__fadd_rn(__fmul_rn(cx, cx), __fmul_rn(cy, cy)),
                               __fmul_rn(cz, cz));
    tab[(size_t)b * NN + p] = make_float4(__fadd_rn(cx, cx), __fadd_rn(cy, cy),
                                          __fadd_rn(cz, cz), sq);
    sorg[(size_t)b * NN + p] = (u32)i;
}

// ---- main grid-pruned scan ----

#define FASTPATH(C, CO) do {                                                  \
    const float inner2_ = __fadd_rn(                                          \
        __fadd_rn(__fmul_rn(qx, (C).x), __fmul_rn(qy, (C).y)),                \
        __fmul_rn(qz, (C).z));                                                \
    float d2_ = __fsub_rn(__fadd_rn(qsq, (C).w), inner2_);                    \
    d2_ = fmaxf(d2_, 0.0f);                                                   \
    const u64 key_ = ((u64)__float_as_uint(d2_) << 32) | (u64)(CO);           \
    buf[cnt][lane] = key_;                                                    \
    cnt += (key_ < wkey) ? 1 : 0;                                             \
} while (0)

struct Tile { u32 st, cn; int cx, cy, cz; int valid; };

__device__ __forceinline__ Tile load_tile(int t0, int lane, int C, int nx, int ny,
                                          int cxlo, int cylo, int czlo,
                                          const u64* __restrict__ descb) {
    Tile r;
    const int ci = t0 + lane;
    r.valid = (ci < C);
    int tx = 0, ty = 0, tz = 0;
    if (r.valid) {
        tx = ci % nx;
        const int t1 = ci / nx;
        ty = t1 % ny;
        tz = t1 / ny;
    }
    r.cx = cxlo + tx; r.cy = cylo + ty; r.cz = czlo + tz;
    r.st = 0u; r.cn = 0u;
    if (r.valid) {
        const u32 m = (part1by2((u32)r.cz) << 2) | (part1by2((u32)r.cy) << 1)
                    | part1by2((u32)r.cx);
        const u64 dd = descb[m];
        r.st = (u32)dd;
        r.cn = (u32)(dd >> 32);
    }
    return r;
}

__global__ __launch_bounds__(BQ) void knn_grid(
    const float4* __restrict__ tab, const u32* __restrict__ sorg,
    const u64* __restrict__ desc, u64* __restrict__ keys)
{
    const int lane = (int)threadIdx.x;
    int bid = blockIdx.x;
    const int sib = bid & (SIBS - 1); bid >>= 2;
    const int b = bid >> 6;
    const int wbegin = (bid & 63) * BQ;              // within-batch sorted slot base
    const float4* tb = tab + (size_t)b * NN;
    const u32* sg = sorg + (size_t)b * NN;
    const u64* descb = desc + (size_t)b * NCM;

    const float4 qv = tb[wbegin + lane];             // (2x,2y,2z,sq)
    const float qx = __fmul_rn(0.5f, qv.x);          // exact
    const float qy = __fmul_rn(0.5f, qv.y);
    const float qz = __fmul_rn(0.5f, qv.z);
    const float qsq = qv.w;

    // wave bounding box of query coords
    float bxlo = qx, bxhi = qx, bylo = qy, byhi = qy, bzlo = qz, bzhi = qz;
#pragma unroll
    for (int off = 32; off; off >>= 1) {
        bxlo = fminf(bxlo, __shfl_xor(bxlo, off)); bxhi = fmaxf(bxhi, __shfl_xor(bxhi, off));
        bylo = fminf(bylo, __shfl_xor(bylo, off)); byhi = fmaxf(byhi, __shfl_xor(byhi, off));
        bzlo = fminf(bzlo, __shfl_xor(bzlo, off)); bzhi = fmaxf(bzhi, __shfl_xor(bzhi, off));
    }

    __shared__ u64 buf[BUFSLOTS][BQ];   // [slot][lane] append buffer
    __shared__ uint2 adesc[BQ];         // compacted accepted-cell (start,cnt)

    u64 list[MAXK];
#pragma unroll
    for (int s = 0; s < MAXK; ++s) list[s] = ~0ull;
    u64 wkey = ~0ull;
    int cnt = 0;

    // Phase A: the wave's own 64 points (includes self). All siblings duplicate
    // this (cheap) to get the per-lane floor + r2 without communication.
#pragma unroll 1
    for (int t = 0; t < BQ; t += 8) {
        if (__any((int)(cnt > BUFSLOTS - 8)))
            flush_buf(list, wkey, cnt, buf, lane, ~0ull);
#pragma unroll
        for (int u = 0; u < 8; ++u) {
            const float4 c = tb[wbegin + t + u];
            const u32 co = sg[wbegin + t + u];
            FASTPATH(c, co);
        }
    }
    flush_buf(list, wkey, cnt, buf, lane, ~0ull);

    const u64 paw = wkey;          // per-lane 16th-best bound (floor from here on)
    if (sib != 0) {
        // Avoid duplicate keys across siblings: only sib 0 keeps phase A's list.
#pragma unroll
        for (int s = 0; s < MAXK; ++s) list[s] = ~0ull;
    }

    // Conservative scan radius: max over lanes of 16th d2, + margin.
    float r2 = __uint_as_float((u32)(paw >> 32));
#pragma unroll
    for (int off = 32; off; off >>= 1) r2 = fmaxf(r2, __shfl_xor(r2, off));
    r2 = __fadd_rn(r2, MARGIN);
    const float r = sqrtf(r2);

    int cxlo = (int)floorf((bxlo - r - GORIG) * GINVW);
    int cxhi = (int)floorf((bxhi + r - GORIG) * GINVW);
    int cylo = (int)floorf((bylo - r - GORIG) * GINVW);
    int cyhi = (int)floorf((byhi + r - GORIG) * GINVW);
    int czlo = (int)floorf((bzlo - r - GORIG) * GINVW);
    int czhi = (int)floorf((bzhi + r - GORIG) * GINVW);
    cxlo = cxlo < 0 ? 0 : cxlo; cxhi = cxhi > NC - 1 ? NC - 1 : cxhi;
    cylo = cylo < 0 ? 0 : cylo; cyhi = cyhi > NC - 1 ? NC - 1 : cyhi;
    czlo = czlo < 0 ? 0 : czlo; czhi = czhi > NC - 1 ? NC - 1 : czhi;
    cxlo = __builtin_amdgcn_readfirstlane(cxlo); cxhi = __builtin_amdgcn_readfirstlane(cxhi);
    cylo = __builtin_amdgcn_readfirstlane(cylo); cyhi = __builtin_amdgcn_readfirstlane(cyhi);
    czlo = __builtin_amdgcn_readfirstlane(czlo); czhi = __builtin_amdgcn_readfirstlane(czhi);

    const int nx = cxhi - cxlo + 1, ny = cyhi - cylo + 1, nz = czhi - czlo + 1;
    const int C = nx * ny * nz;
    const u64 lmask = (1ull << lane) - 1ull;

    // Phase B: tiled parallel cell-accept (pure VALU geometry; descriptors
    // preloaded 64-wide one tile ahead), LDS compaction, ordinal round-robin
    // deal to the 4 siblings, then candidate streaming.
    Tile cur = load_tile(0, lane, C, nx, ny, czlo /*dummy: fixed below*/, 0, 0, descb);
    // NOTE: call again with correct args (avoid accidental misuse above)
    cur = load_tile(0, lane, C, nx, ny, cxlo, cylo, czlo, descb);
    int ordinal = 0;
#pragma unroll 1
    for (int t0 = 0; t0 < C; t0 += BQ) {
        Tile nxt;
        if (t0 + BQ < C) {
            nxt = load_tile(t0 + BQ, lane, C, nx, ny, cxlo, cylo, czlo, descb);
        } else {
            nxt.valid = 0; nxt.st = 0; nxt.cn = 0; nxt.cx = 0; nxt.cy = 0; nxt.cz = 0;
        }
        // geometric acceptance for cur's cell (open-ended border AABBs)
        bool acc = (cur.valid != 0) && (cur.cn > 0u);
        if (acc) {
            float xlo = GORIG + cur.cx * GW, xhi = xlo + GW;
            if (cur.cx == 0) xlo = -1e30f;
            if (cur.cx == NC - 1) xhi = 1e30f;
            float ylo = GORIG + cur.cy * GW, yhi = ylo + GW;
            if (cur.cy == 0) ylo = -1e30f;
            if (cur.cy == NC - 1) yhi = 1e30f;
            float zlo = GORIG + cur.cz * GW, zhi = zlo + GW;
            if (cur.cz == 0) zlo = -1e30f;
            if (cur.cz == NC - 1) zhi = 1e30f;
            const float dx = fmaxf(fmaxf(xlo - bxhi, bxlo - xhi), 0.0f);
            const float dy = fmaxf(fmaxf(ylo - byhi, bylo - yhi), 0.0f);
            const float dz = fmaxf(fmaxf(zlo - bzhi, bzlo - zhi), 0.0f);
            acc = (dx * dx + dy * dy + dz * dz) <= r2;
        }
        const u64 bal = __ballot((int)acc);
        const int na = (int)__popcll(bal);
        if (acc) {
            const int pos = (int)__popcll(bal & lmask);
            adesc[pos] = make_uint2(cur.st, cur.cn);
        }
        __builtin_amdgcn_wave_barrier();
        // stream this tile's accepted cells (ordinal round-robin across sibs)
#pragma unroll 1
        for (int e = 0; e < na; ++e) {
            if (((ordinal + e) & (SIBS - 1)) != sib) continue;
            const uint2 dd = adesc[e];       // wave-uniform broadcast read
            const u32 st = dd.x, cn = dd.y;
#pragma unroll 1
            for (u32 o = 0; o < cn; o += 4) {
                if (__any((int)(cnt > BUFSLOTS - 4)))
                    flush_buf(list, wkey, cnt, buf, lane, paw);
                const u32 en = (o + 4u < cn) ? o + 4u : cn;
                for (u32 ii = o; ii < en; ++ii) {
                    const int s = (int)(st + ii);
                    if (s >= wbegin && s < wbegin + BQ) continue;  // phase A did these
                    const float4 c = tb[s];
                    const u32 co = sg[s];
                    FASTPATH(c, co);
                }
            }
        }
        __builtin_amdgcn_wave_barrier();
        ordinal += na;
        cur = nxt;
    }
    flush_buf(list, wkey, cnt, buf, lane, paw);

    // Coalesced sorted-slot-indexed key dump; merge maps sorted->orig.
    const size_t qs = (size_t)b * NN + wbegin + lane;
#pragma unroll
    for (int s = 0; s < MAXK; ++s)
        keys[(size_t)(sib * MAXK + s) * (BB * NN) + qs] = list[s];
}

__global__ __launch_bounds__(256) void knn_merge4(
    const float* __restrict__ preds, const float* __restrict__ kvec,
    const u64* __restrict__ keys, const u32* __restrict__ sorg,
    float* __restrict__ out)
{
    const int qs = blockIdx.x * 256 + (int)threadIdx.x;   // sorted slot, 0..B*N-1

    u64 list[MAXK];
#pragma unroll
    for (int s = 0; s < MAXK; ++s)
        list[s] = keys[(size_t)s * (BB * NN) + qs];        // coalesced
#pragma unroll 1
    for (int g = 1; g < SIBS; ++g) {
        u64 br[MAXK];
#pragma unroll
        for (int s = 0; s < MAXK; ++s)
            br[s] = keys[(size_t)(g * MAXK + s) * (BB * NN) + qs];
        merge16(list, br);
    }

    const int b = qs >> 12;
    const int qorig = (int)sorg[qs];
    write_mean(preds + (size_t)b * NN * 3, kvec, list,
               out + ((size_t)b * NN + qorig) * 3);
}

// ---- fallback: fused brute force (no workspace), known-good structure ----
__global__ __launch_bounds__(BQ) void knn_brute(
    const float* __restrict__ x, const float* __restrict__ preds,
    const float* __restrict__ kvec, float* __restrict__ out)
{
    const int lane = (int)threadIdx.x;
    const int qg = blockIdx.x % (NN / BQ);
    const int b  = blockIdx.x / (NN / BQ);
    const int qi = qg * BQ + lane;
    const float* xb = x + (size_t)b * NN * 3;
    const float qx = xb[qi * 3 + 0], qy = xb[qi * 3 + 1], qz = xb[qi * 3 + 2];
    const float qsq = __fadd_rn(__fadd_rn(__fmul_rn(qx, qx), __fmul_rn(qy, qy)),
                                __fmul_rn(qz, qz));
    __shared__ u64 buf[BUFSLOTS][BQ];
    u64 list[MAXK];
#pragma unroll
    for (int s = 0; s < MAXK; ++s) list[s] = ~0ull;
    u64 wkey = ~0ull;
    int cnt = 0;
#pragma unroll 1
    for (int t = 0; t < NN; t += 4) {
        if (__any((int)(cnt > BUFSLOTS - 4))) flush_buf(list, wkey, cnt, buf, lane, ~0ull);
#pragma unroll
        for (int u = 0; u < 4; ++u) {
            const int j = t + u;
            const float cx = xb[j * 3 + 0], cy = xb[j * 3 + 1], cz = xb[j * 3 + 2];
            const float csq = __fadd_rn(__fadd_rn(__fmul_rn(cx, cx), __fmul_rn(cy, cy)),
                                        __fmul_rn(cz, cz));
            const float inner = __fadd_rn(
                __fadd_rn(__fmul_rn(qx, cx), __fmul_rn(qy, cy)), __fmul_rn(qz, cz));
            float d2 = __fsub_rn(__fadd_rn(qsq, csq), __fmul_rn(2.0f, inner));
            d2 = fmaxf(d2, 0.0f);
            const u64 key = ((u64)__float_as_uint(d2) << 32) | (u32)j;
            buf[cnt][lane] = key;
            cnt += (key < wkey) ? 1 : 0;
        }
    }
    flush_buf(list, wkey, cnt, buf, lane, ~0ull);
    write_mean(preds + (size_t)b * NN * 3, kvec, list,
               out + ((size_t)b * NN + qi) * 3);
}

extern "C" void kernel_launch(void* const* d_in, const int* in_sizes, int n_in,
                              void* d_out, int out_size, void* d_ws, size_t ws_size,
                              hipStream_t stream) {
    (void)in_sizes; (void)n_in; (void)out_size;
    const float* x     = (const float*)d_in[0];
    const float* preds = (const float*)d_in[1];
    const float* kvec  = (const float*)d_in[2];
    float* out = (float*)d_out;

    if (ws_size >= (size_t)WS_NEED) {
        char* w = (char*)d_ws;
        float4* tab  = (float4*)(w + OFF_TAB);
        u64* keys    = (u64*)(w + OFF_KEYS);
        u64* descp   = (u64*)(w + OFF_DESC);
        u32* hist    = (u32*)(w + OFF_HIST);
        u32* cursor  = (u32*)(w + OFF_CUR);
        u32* ids     = (u32*)(w + OFF_IDS);
        u32* sorg    = (u32*)(w + OFF_SORG);

        knn_zero<<<(BB * NCM) / 256, 256, 0, stream>>>(hist, BB * NCM);
        knn_build<<<(BB * NN) / 256, 256, 0, stream>>>(x, hist, ids);
        knn_prefix<<<BB, 1024, 0, stream>>>(hist, descp, cursor);
        knn_scatter<<<(BB * NN) / 256, 256, 0, stream>>>(x, ids, cursor, tab, sorg);
        knn_grid<<<BB * (NN / BQ) * SIBS, BQ, 0, stream>>>(tab, sorg, descp, keys);
        knn_merge4<<<(BB * NN) / 256, 256, 0, stream>>>(preds, kvec, keys, sorg, out);
    } else {
        knn_brute<<<BB * (NN / BQ), BQ, 0, stream>>>(x, preds, kvec, out);
    }
}

// Round 8
// 426.489 us; speedup vs baseline: 3.1713x; 1.0826x over previous
//
#include <hip/hip_runtime.h>
#include <math.h>

typedef unsigned long long u64;
typedef unsigned int u32;

#define BB 8
#define NN 4096
#define MAXK 16
#define BQ 64          // one wave per block
#define BUFSLOTS 16    // per-lane LDS append buffer (8 KB/block)
#define SIBS 4         // sibling blocks per query wave
#define NGR 4          // 16-lane subgroups per wave

// spatial grid
#define NC 24
#define NCM (1 << 15)  // morton cell id space (5 bits/axis)
#define GORIG (-4.2f)
#define GW 0.35f
#define GINVW (1.0f / GW)
// Pruning margin: covers |d2_fp - d2_true| (<= ~2e-5) with large slack.
#define MARGIN 2.0e-3f

// ---- ws layout (byte offsets; ~20.8 MiB total) ----
#define OFF_TAB   0                                       // float4[BB*NN] (2x,2y,2z,sq)
#define OFF_KEYS  (OFF_TAB + BB * NN * 16)                // u64[SIBS*16][BB*NN]
#define OFF_DESC  (OFF_KEYS + SIBS * MAXK * BB * NN * 8)  // u64[BB*NCM] (cnt<<32)|start
#define OFF_HIST  (OFF_DESC + BB * NCM * 8)               // u32[BB*NCM]
#define OFF_CUR   (OFF_HIST + BB * NCM * 4)               // u32[BB*NCM]
#define OFF_IDS   (OFF_CUR + BB * NCM * 4)                // u32[BB*NN] morton id per point
#define OFF_SORG  (OFF_IDS + BB * NN * 4)                 // u32[BB*NN] sorted->orig
#define WS_NEED   (OFF_SORG + BB * NN * 4)

__device__ __forceinline__ u32 part1by2(u32 x) {
    x &= 0x3FF;
    x = (x | (x << 16)) & 0x030000FF;
    x = (x | (x << 8))  & 0x0300F00F;
    x = (x | (x << 4))  & 0x030C30C3;
    x = (x | (x << 2))  & 0x09249249;
    return x;
}

// ---- branch-free in-register top-16 machinery (u64 keys, ascending) ----

__device__ __forceinline__ void bitonic16(u64 v[MAXK]) {
#pragma unroll
    for (int k = 2; k <= 16; k <<= 1) {
#pragma unroll
        for (int j = k >> 1; j > 0; j >>= 1) {
#pragma unroll
            for (int i = 0; i < 16; ++i) {
                const int l = i ^ j;
                if (l > i) {
                    const u64 a = v[i], b = v[l];
                    const bool up = ((i & k) == 0);
                    const bool sw = up ? (a > b) : (a < b);
                    v[i] = sw ? b : a;
                    v[l] = sw ? a : b;
                }
            }
        }
    }
}

__device__ __forceinline__ void merge16(u64 list[MAXK], const u64 br[MAXK]) {
    u64 lo[MAXK];
#pragma unroll
    for (int i = 0; i < 16; ++i) {
        const u64 a = list[i], b = br[15 - i];
        lo[i] = a < b ? a : b;
    }
#pragma unroll
    for (int j = 8; j > 0; j >>= 1) {
#pragma unroll
        for (int i = 0; i < 16; ++i) {
            const int l = i ^ j;
            if (l > i) {
                const u64 a = lo[i], b = lo[l];
                const bool sw = a > b;
                lo[i] = sw ? b : a;
                lo[l] = sw ? a : b;
            }
        }
    }
#pragma unroll
    for (int i = 0; i < 16; ++i) list[i] = lo[i];
}

// floorv: append-filter floor (per-lane); wkey = min(list[15], floorv).
__device__ __forceinline__ void flush_buf(u64 list[MAXK], u64& wkey, int& cnt,
                                          const u64 (*buf)[BQ], int lane, u64 floorv) {
    u64 br[MAXK];
#pragma unroll
    for (int i = 0; i < 16; ++i) {
        const u64 v = buf[i][lane];
        br[i] = (i < cnt) ? v : ~0ull;
    }
    bitonic16(br);
    merge16(list, br);
    const u64 l15 = list[15];
    wkey = l15 < floorv ? l15 : floorv;
    cnt = 0;
}

// k = argmax(kvec)+1 (first index wins), gather preds of selected, mean.
__device__ __forceinline__ void write_mean(const float* __restrict__ pb,
                                           const float* __restrict__ kvec,
                                           const u64 list[MAXK],
                                           float* __restrict__ op) {
    float bv = kvec[0]; int bi = 0;
#pragma unroll
    for (int i = 1; i < MAXK; ++i) { const float v = kvec[i]; if (v > bv) { bv = v; bi = i; } }
    const int k = bi + 1;
    float sx = 0.f, sy = 0.f, sz = 0.f;
#pragma unroll
    for (int s = 0; s < MAXK; ++s) {
        if (s < k) {
            const int j = (int)(u32)list[s];
            sx = __fadd_rn(sx, pb[j * 3 + 0]);
            sy = __fadd_rn(sy, pb[j * 3 + 1]);
            sz = __fadd_rn(sz, pb[j * 3 + 2]);
        }
    }
    const float fk = (float)k;
    op[0] = __fdiv_rn(sx, fk);
    op[1] = __fdiv_rn(sy, fk);
    op[2] = __fdiv_rn(sz, fk);
}

// ---- build kernels ----

__global__ __launch_bounds__(256) void knn_zero(u32* __restrict__ p, int n) {
    const int i = blockIdx.x * 256 + (int)threadIdx.x;
    if (i < n) p[i] = 0u;
}

__global__ __launch_bounds__(256) void knn_build(const float* __restrict__ x,
                                                 u32* __restrict__ hist,
                                                 u32* __restrict__ ids) {
    const int g = blockIdx.x * 256 + (int)threadIdx.x;   // 0 .. BB*NN-1
    const int b = g >> 12;
    const float px = x[(size_t)g * 3 + 0];
    const float py = x[(size_t)g * 3 + 1];
    const float pz = x[(size_t)g * 3 + 2];
    int cx = (int)floorf((px - GORIG) * GINVW); cx = cx < 0 ? 0 : (cx > NC - 1 ? NC - 1 : cx);
    int cy = (int)floorf((py - GORIG) * GINVW); cy = cy < 0 ? 0 : (cy > NC - 1 ? NC - 1 : cy);
    int cz = (int)floorf((pz - GORIG) * GINVW); cz = cz < 0 ? 0 : (cz > NC - 1 ? NC - 1 : cz);
    const u32 m = (part1by2((u32)cz) << 2) | (part1by2((u32)cy) << 1) | part1by2((u32)cx);
    ids[g] = m;
    atomicAdd(&hist[b * NCM + (int)m], 1u);
}

// Exclusive prefix per batch; emits packed desc = (count<<32)|start and cursor.
__global__ __launch_bounds__(1024) void knn_prefix(const u32* __restrict__ hist,
                                                   u64* __restrict__ desc,
                                                   u32* __restrict__ cursor) {
    const int b = blockIdx.x;
    const int tid = (int)threadIdx.x;
    const int lane = tid & 63, wid = tid >> 6;
    __shared__ u32 wsum[16];
    u32 carry = 0;
    for (int c0 = 0; c0 < NCM; c0 += 4096) {
        const int base = b * NCM + c0 + tid * 4;
        const uint4 v = *(const uint4*)(hist + base);
        const u32 s0 = v.x, s1 = s0 + v.y, s2 = s1 + v.z, s3 = s2 + v.w;
        u32 inc = s3;
#pragma unroll
        for (int off = 1; off < 64; off <<= 1) {
            const u32 n = __shfl_up(inc, off);
            if (lane >= off) inc += n;
        }
        if (lane == 63) wsum[wid] = inc;
        __syncthreads();
        if (wid == 0) {
            u32 s = (lane < 16) ? wsum[lane] : 0u;
#pragma unroll
            for (int off = 1; off < 16; off <<= 1) {
                const u32 n = __shfl_up(s, off);
                if (lane >= off) s += n;
            }
            if (lane < 16) wsum[lane] = s;
        }
        __syncthreads();
        const u32 woff = wid ? wsum[wid - 1] : 0u;
        const u32 tot = wsum[15];
        const u32 excl = carry + woff + (inc - s3);
        const u32 st0 = excl, st1 = excl + s0, st2 = excl + s1, st3 = excl + s2;
        desc[base + 0] = ((u64)v.x << 32) | st0;
        desc[base + 1] = ((u64)v.y << 32) | st1;
        desc[base + 2] = ((u64)v.z << 32) | st2;
        desc[base + 3] = ((u64)v.w << 32) | st3;
        cursor[base + 0] = st0; cursor[base + 1] = st1;
        cursor[base + 2] = st2; cursor[base + 3] = st3;
        __syncthreads();
        carry += tot;
    }
}

__global__ __launch_bounds__(256) void knn_scatter(const float* __restrict__ x,
                                                   const u32* __restrict__ ids,
                                                   u32* __restrict__ cursor,
                                                   float4* __restrict__ tab,
                                                   u32* __restrict__ sorg) {
    const int g = blockIdx.x * 256 + (int)threadIdx.x;
    const int b = g >> 12, i = g & (NN - 1);
    const u32 id = ids[g];
    const u32 p = atomicAdd(&cursor[b * NCM + (int)id], 1u);   // batch-local slot
    const float cx = x[(size_t)g * 3 + 0];
    const float cy = x[(size_t)g * 3 + 1];
    const float cz = x[(size_t)g * 3 + 2];
    const float sq = __fadd_rn(__fadd_rn(__fmul_rn(cx, cx), __fmul_rn(cy, cy)),
                               __fmul_rn(cz, cz));
    tab[(size_t)b * NN + p] = make_float4(__fadd_rn(cx, cx), __fadd_rn(cy, cy),
                                          __fadd_rn(cz, cz), sq);
    sorg[(size_t)b * NN + p] = (u32)i;
}

// ---- main grid-pruned scan ----

#define FASTPATH(C, CO) do {                                                  \
    const float inner2_ = __fadd_rn(                                          \
        __fadd_rn(__fmul_rn(qx, (C).x), __fmul_rn(qy, (C).y)),                \
        __fmul_rn(qz, (C).z));                                                \
    float d2_ = __fsub_rn(__fadd_rn(qsq, (C).w), inner2_);                    \
    d2_ = fmaxf(d2_, 0.0f);                                                   \
    const u64 key_ = ((u64)__float_as_uint(d2_) << 32) | (u64)(CO);           \
    buf[cnt][lane] = key_;                                                    \
    cnt += (key_ < wkey) ? 1 : 0;                                             \
} while (0)

struct Tile { u32 st, cn; int cx, cy, cz; int valid; };

__device__ __forceinline__ Tile load_tile(int t0, int lane, int C, int nx, int ny,
                                          int cxlo, int cylo, int czlo,
                                          const u64* __restrict__ descb) {
    Tile r;
    const int ci = t0 + lane;
    r.valid = (ci < C);
    int tx = 0, ty = 0, tz = 0;
    if (r.valid) {
        tx = ci % nx;
        const int t1 = ci / nx;
        ty = t1 % ny;
        tz = t1 / ny;
    }
    r.cx = cxlo + tx; r.cy = cylo + ty; r.cz = czlo + tz;
    r.st = 0u; r.cn = 0u;
    if (r.valid) {
        const u32 m = (part1by2((u32)r.cz) << 2) | (part1by2((u32)r.cy) << 1)
                    | part1by2((u32)r.cx);
        const u64 dd = descb[m];
        r.st = (u32)dd;
        r.cn = (u32)(dd >> 32);
    }
    return r;
}

__global__ __launch_bounds__(BQ) void knn_grid(
    const float4* __restrict__ tab, const u32* __restrict__ sorg,
    const u64* __restrict__ desc, u64* __restrict__ keys)
{
    const int lane = (int)threadIdx.x;
    int bid = blockIdx.x;
    const int sib = bid & (SIBS - 1); bid >>= 2;
    const int b = bid >> 6;
    const int wbegin = (bid & 63) * BQ;              // within-batch sorted slot base
    const float4* tb = tab + (size_t)b * NN;
    const u32* sg = sorg + (size_t)b * NN;
    const u64* descb = desc + (size_t)b * NCM;

    const float4 qv = tb[wbegin + lane];             // (2x,2y,2z,sq)
    const float qx = __fmul_rn(0.5f, qv.x);          // exact
    const float qy = __fmul_rn(0.5f, qv.y);
    const float qz = __fmul_rn(0.5f, qv.z);
    const float qsq = qv.w;
    const u32 qorig = sg[wbegin + lane];

    __shared__ u64 buf[BUFSLOTS][BQ];   // [slot][lane] append buffer
    __shared__ float4 cpos[BQ];         // staged candidates (2x,2y,2z,sq)
    __shared__ u32 cidx[BQ];            // staged candidate orig indices
    __shared__ u32 myq_st[BQ];          // my accepted cells: start
    __shared__ u32 myq_cn[BQ];          // my accepted cells: count
    __shared__ u32 myq_off[BQ];         // exclusive candidate offsets
    __shared__ float gbox[NGR][8];      // per-subgroup lo3, hi3, r2, r

    u64 list[MAXK];
#pragma unroll
    for (int s = 0; s < MAXK; ++s) list[s] = ~0ull;
    u64 wkey = ~0ull;
    int cnt = 0;

    // Phase A: the wave's own 64 points, staged for free from registers.
    cpos[lane] = qv; cidx[lane] = qorig;
    __builtin_amdgcn_wave_barrier();
#pragma unroll 1
    for (int t = 0; t < BQ; t += 4) {
        if (__any((int)(cnt > BUFSLOTS - 4)))
            flush_buf(list, wkey, cnt, buf, lane, ~0ull);
#pragma unroll
        for (int u = 0; u < 4; ++u) {
            const float4 c = cpos[t + u];            // LDS broadcast
            const u32 co = cidx[t + u];
            FASTPATH(c, co);
        }
    }
    flush_buf(list, wkey, cnt, buf, lane, ~0ull);

    const u64 paw = wkey;          // per-lane 16th-best bound (floor from here on)
    if (sib != 0) {
        // Only sib 0 keeps phase A's list (no duplicate keys across siblings).
#pragma unroll
        for (int s = 0; s < MAXK; ++s) list[s] = ~0ull;
    }

    // Per-subgroup (16 Morton-adjacent lanes) boxes + conservative radii.
    {
        const float d16 = __uint_as_float((u32)(paw >> 32));
        float lx = qx, hx = qx, ly = qy, hy = qy, lz = qz, hz = qz;
        float r2g = __fadd_rn(d16, MARGIN);
#pragma unroll
        for (int off = 1; off < 16; off <<= 1) {
            lx = fminf(lx, __shfl_xor(lx, off)); hx = fmaxf(hx, __shfl_xor(hx, off));
            ly = fminf(ly, __shfl_xor(ly, off)); hy = fmaxf(hy, __shfl_xor(hy, off));
            lz = fminf(lz, __shfl_xor(lz, off)); hz = fmaxf(hz, __shfl_xor(hz, off));
            r2g = fmaxf(r2g, __shfl_xor(r2g, off));
        }
        if ((lane & 15) == 0) {
            const int g = lane >> 4;
            gbox[g][0] = lx; gbox[g][1] = ly; gbox[g][2] = lz;
            gbox[g][3] = hx; gbox[g][4] = hy; gbox[g][5] = hz;
            gbox[g][6] = r2g; gbox[g][7] = sqrtf(r2g);
        }
    }
    __builtin_amdgcn_wave_barrier();
    float aglx[NGR], agly[NGR], aglz[NGR], aghx[NGR], aghy[NGR], aghz[NGR];
    float agr2[NGR], agr[NGR];
#pragma unroll
    for (int g = 0; g < NGR; ++g) {
        aglx[g] = gbox[g][0]; agly[g] = gbox[g][1]; aglz[g] = gbox[g][2];
        aghx[g] = gbox[g][3]; aghy[g] = gbox[g][4]; aghz[g] = gbox[g][5];
        agr2[g] = gbox[g][6]; agr[g]  = gbox[g][7];
    }

    // Enumeration box: union over subgroups of [lo - r, hi + r].
    float exl = 1e30f, exh = -1e30f, eyl = 1e30f, eyh = -1e30f, ezl = 1e30f, ezh = -1e30f;
#pragma unroll
    for (int g = 0; g < NGR; ++g) {
        exl = fminf(exl, aglx[g] - agr[g]); exh = fmaxf(exh, aghx[g] + agr[g]);
        eyl = fminf(eyl, agly[g] - agr[g]); eyh = fmaxf(eyh, aghy[g] + agr[g]);
        ezl = fminf(ezl, aglz[g] - agr[g]); ezh = fmaxf(ezh, aghz[g] + agr[g]);
    }
    int cxlo = (int)floorf((exl - GORIG) * GINVW);
    int cxhi = (int)floorf((exh - GORIG) * GINVW);
    int cylo = (int)floorf((eyl - GORIG) * GINVW);
    int cyhi = (int)floorf((eyh - GORIG) * GINVW);
    int czlo = (int)floorf((ezl - GORIG) * GINVW);
    int czhi = (int)floorf((ezh - GORIG) * GINVW);
    cxlo = cxlo < 0 ? 0 : cxlo; cxhi = cxhi > NC - 1 ? NC - 1 : cxhi;
    cylo = cylo < 0 ? 0 : cylo; cyhi = cyhi > NC - 1 ? NC - 1 : cyhi;
    czlo = czlo < 0 ? 0 : czlo; czhi = czhi > NC - 1 ? NC - 1 : czhi;
    cxlo = __builtin_amdgcn_readfirstlane(cxlo); cxhi = __builtin_amdgcn_readfirstlane(cxhi);
    cylo = __builtin_amdgcn_readfirstlane(cylo); cyhi = __builtin_amdgcn_readfirstlane(cyhi);
    czlo = __builtin_amdgcn_readfirstlane(czlo); czhi = __builtin_amdgcn_readfirstlane(czhi);

    const int nx = cxhi - cxlo + 1, ny = cyhi - cylo + 1, nz = czhi - czlo + 1;
    const int C = nx * ny * nz;
    const u64 lmask = (1ull << lane) - 1ull;

    Tile cur = load_tile(0, lane, C, nx, ny, cxlo, cylo, czlo, descb);
    int ordinal = 0;
#pragma unroll 1
    for (int t0 = 0; t0 < C; t0 += BQ) {
        Tile nxt;
        if (t0 + BQ < C) {
            nxt = load_tile(t0 + BQ, lane, C, nx, ny, cxlo, cylo, czlo, descb);
        } else {
            nxt.valid = 0; nxt.st = 0; nxt.cn = 0; nxt.cx = 0; nxt.cy = 0; nxt.cz = 0;
        }
        // Geometric acceptance vs any subgroup ball (open-ended border AABBs).
        bool acc = (cur.valid != 0) && (cur.cn > 0u);
        if (acc) {
            float xlo = GORIG + cur.cx * GW, xhi = xlo + GW;
            if (cur.cx == 0) xlo = -1e30f;
            if (cur.cx == NC - 1) xhi = 1e30f;
            float ylo = GORIG + cur.cy * GW, yhi = ylo + GW;
            if (cur.cy == 0) ylo = -1e30f;
            if (cur.cy == NC - 1) yhi = 1e30f;
            float zlo = GORIG + cur.cz * GW, zhi = zlo + GW;
            if (cur.cz == 0) zlo = -1e30f;
            if (cur.cz == NC - 1) zhi = 1e30f;
            bool any = false;
#pragma unroll
            for (int g = 0; g < NGR; ++g) {
                const float dx = fmaxf(fmaxf(xlo - aghx[g], aglx[g] - xhi), 0.0f);
                const float dy = fmaxf(fmaxf(ylo - aghy[g], agly[g] - yhi), 0.0f);
                const float dz = fmaxf(fmaxf(zlo - aghz[g], aglz[g] - zhi), 0.0f);
                any = any || ((dx * dx + dy * dy + dz * dz) <= agr2[g]);
            }
            acc = any;
        }
        const u64 bal = __ballot((int)acc);
        const int na = (int)__popcll(bal);
        const int pos = (int)__popcll(bal & lmask);
        const bool mine = acc && (((ordinal + pos) & (SIBS - 1)) == sib);
        const u64 bal2 = __ballot((int)mine);
        const int mym = (int)__popcll(bal2);
        if (mine) {
            const int mp = (int)__popcll(bal2 & lmask);
            myq_st[mp] = cur.st; myq_cn[mp] = cur.cn;
        }
        __builtin_amdgcn_wave_barrier();
        if (mym > 0) {
            // Exclusive prefix of candidate counts over my cells.
            const u32 val = (lane < mym) ? myq_cn[lane] : 0u;
            u32 inc = val;
#pragma unroll
            for (int off = 1; off < 64; off <<= 1) {
                const u32 n = __shfl_up(inc, off);
                if (lane >= off) inc += n;
            }
            if (lane < mym) myq_off[lane] = inc - val;
            const u32 G = (u32)__shfl((int)inc, 63);
            __builtin_amdgcn_wave_barrier();

            // Drain in chunks of 64: cooperative gather -> LDS -> all-lane stream.
#pragma unroll 1
            for (u32 g0 = 0; g0 < G; g0 += BQ) {
                const u32 g = g0 + (u32)lane;
                const bool vld = (g < G);
                const u32 gg = vld ? g : (G - 1u);
                int p = 0;
#pragma unroll
                for (int stp = 32; stp; stp >>= 1) {
                    const int np = p + stp;
                    if (np < mym && myq_off[np] <= gg) p = np;
                }
                const u32 s = myq_st[p] + (gg - myq_off[p]);
                const bool own = (s >= (u32)wbegin) && (s < (u32)(wbegin + BQ));
                float4 c; u32 co;
                if (vld && !own) {
                    c = tb[s];                        // 64-wide parallel gather
                    co = sg[s];
                } else {
                    c = make_float4(0.0f, 0.0f, 0.0f, INFINITY);  // key can't win
                    co = 0u;
                }
                cpos[lane] = c; cidx[lane] = co;
                __builtin_amdgcn_wave_barrier();
                const int nc = (int)(((G - g0) < (u32)BQ) ? (G - g0) : (u32)BQ);
#pragma unroll 1
                for (int t = 0; t < nc; t += 4) {
                    if (__any((int)(cnt > BUFSLOTS - 4)))
                        flush_buf(list, wkey, cnt, buf, lane, paw);
#pragma unroll
                    for (int u = 0; u < 4; ++u) {
                        if (t + u < nc) {
                            const float4 cc = cpos[t + u];   // LDS broadcast
                            const u32 cco = cidx[t + u];
                            FASTPATH(cc, cco);
                        }
                    }
                }
                __builtin_amdgcn_wave_barrier();
            }
        }
        ordinal += na;
        cur = nxt;
    }
    flush_buf(list, wkey, cnt, buf, lane, paw);

    // Coalesced sorted-slot-indexed key dump; merge maps sorted->orig.
    const size_t qs = (size_t)b * NN + wbegin + lane;
#pragma unroll
    for (int s = 0; s < MAXK; ++s)
        keys[(size_t)(sib * MAXK + s) * (BB * NN) + qs] = list[s];
}

__global__ __launch_bounds__(256) void knn_merge4(
    const float* __restrict__ preds, const float* __restrict__ kvec,
    const u64* __restrict__ keys, const u32* __restrict__ sorg,
    float* __restrict__ out)
{
    const int qs = blockIdx.x * 256 + (int)threadIdx.x;   // sorted slot, 0..B*N-1

    u64 list[MAXK];
#pragma unroll
    for (int s = 0; s < MAXK; ++s)
        list[s] = keys[(size_t)s * (BB * NN) + qs];        // coalesced
#pragma unroll 1
    for (int g = 1; g < SIBS; ++g) {
        u64 br[MAXK];
#pragma unroll
        for (int s = 0; s < MAXK; ++s)
            br[s] = keys[(size_t)(g * MAXK + s) * (BB * NN) + qs];
        merge16(list, br);
    }

    const int b = qs >> 12;
    const int qorig = (int)sorg[qs];
    write_mean(preds + (size_t)b * NN * 3, kvec, list,
               out + ((size_t)b * NN + qorig) * 3);
}

// ---- fallback: fused brute force (no workspace), known-good structure ----
__global__ __launch_bounds__(BQ) void knn_brute(
    const float* __restrict__ x, const float* __restrict__ preds,
    const float* __restrict__ kvec, float* __restrict__ out)
{
    const int lane = (int)threadIdx.x;
    const int qg = blockIdx.x % (NN / BQ);
    const int b  = blockIdx.x / (NN / BQ);
    const int qi = qg * BQ + lane;
    const float* xb = x + (size_t)b * NN * 3;
    const float qx = xb[qi * 3 + 0], qy = xb[qi * 3 + 1], qz = xb[qi * 3 + 2];
    const float qsq = __fadd_rn(__fadd_rn(__fmul_rn(qx, qx), __fmul_rn(qy, qy)),
                                __fmul_rn(qz, qz));
    __shared__ u64 buf[BUFSLOTS][BQ];
    u64 list[MAXK];
#pragma unroll
    for (int s = 0; s < MAXK; ++s) list[s] = ~0ull;
    u64 wkey = ~0ull;
    int cnt = 0;
#pragma unroll 1
    for (int t = 0; t < NN; t += 4) {
        if (__any((int)(cnt > BUFSLOTS - 4))) flush_buf(list, wkey, cnt, buf, lane, ~0ull);
#pragma unroll
        for (int u = 0; u < 4; ++u) {
            const int j = t + u;
            const float cx = xb[j * 3 + 0], cy = xb[j * 3 + 1], cz = xb[j * 3 + 2];
            const float csq = __fadd_rn(__fadd_rn(__fmul_rn(cx, cx), __fmul_rn(cy, cy)),
                                        __fmul_rn(cz, cz));
            const float inner = __fadd_rn(
                __fadd_rn(__fmul_rn(qx, cx), __fmul_rn(qy, cy)), __fmul_rn(qz, cz));
            float d2 = __fsub_rn(__fadd_rn(qsq, csq), __fmul_rn(2.0f, inner));
            d2 = fmaxf(d2, 0.0f);
            const u64 key = ((u64)__float_as_uint(d2) << 32) | (u32)j;
            buf[cnt][lane] = key;
            cnt += (key < wkey) ? 1 : 0;
        }
    }
    flush_buf(list, wkey, cnt, buf, lane, ~0ull);
    write_mean(preds + (size_t)b * NN * 3, kvec, list,
               out + ((size_t)b * NN + qi) * 3);
}

extern "C" void kernel_launch(void* const* d_in, const int* in_sizes, int n_in,
                              void* d_out, int out_size, void* d_ws, size_t ws_size,
                              hipStream_t stream) {
    (void)in_sizes; (void)n_in; (void)out_size;
    const float* x     = (const float*)d_in[0];
    const float* preds = (const float*)d_in[1];
    const float* kvec  = (const float*)d_in[2];
    float* out = (float*)d_out;

    if (ws_size >= (size_t)WS_NEED) {
        char* w = (char*)d_ws;
        float4* tab  = (float4*)(w + OFF_TAB);
        u64* keys    = (u64*)(w + OFF_KEYS);
        u64* descp   = (u64*)(w + OFF_DESC);
        u32* hist    = (u32*)(w + OFF_HIST);
        u32* cursor  = (u32*)(w + OFF_CUR);
        u32* ids     = (u32*)(w + OFF_IDS);
        u32* sorg    = (u32*)(w + OFF_SORG);

        knn_zero<<<(BB * NCM) / 256, 256, 0, stream>>>(hist, BB * NCM);
        knn_build<<<(BB * NN) / 256, 256, 0, stream>>>(x, hist, ids);
        knn_prefix<<<BB, 1024, 0, stream>>>(hist, descp, cursor);
        knn_scatter<<<(BB * NN) / 256, 256, 0, stream>>>(x, ids, cursor, tab, sorg);
        knn_grid<<<BB * (NN / BQ) * SIBS, BQ, 0, stream>>>(tab, sorg, descp, keys);
        knn_merge4<<<(BB * NN) / 256, 256, 0, stream>>>(preds, kvec, keys, sorg, out);
    } else {
        knn_brute<<<BB * (NN / BQ), BQ, 0, stream>>>(x, preds, kvec, out);
    }
}

// Round 9
// 289.214 us; speedup vs baseline: 4.6765x; 1.4746x over previous
//
#include <hip/hip_runtime.h>
#include <math.h>

typedef unsigned long long u64;
typedef unsigned int u32;

#define BB 8
#define NN 4096
#define MAXK 16
#define BQ 64          // one wave per block
#define BUFSLOTS 16    // per-lane LDS append buffer (8 KB/block)

// spatial grid
#define NC 24
#define NCM (1 << 15)  // morton cell id space (5 bits/axis)
#define GORIG (-4.2f)
#define GW 0.35f
#define GINVW (1.0f / GW)
// Pruning margin: covers |d2_fp - d2_true| (<= ~2e-5) with large slack.
#define MARGIN 2.0e-3f

__device__ __forceinline__ u32 part1by2(u32 x) {
    x &= 0x3FF;
    x = (x | (x << 16)) & 0x030000FF;
    x = (x | (x << 8))  & 0x0300F00F;
    x = (x | (x << 4))  & 0x030C30C3;
    x = (x | (x << 2))  & 0x09249249;
    return x;
}
__device__ __forceinline__ u32 morton3(int cx, int cy, int cz) {
    return (part1by2((u32)cz) << 2) | (part1by2((u32)cy) << 1) | part1by2((u32)cx);
}

// ---- branch-free in-register top-16 machinery (u64 keys, ascending) ----

__device__ __forceinline__ void bitonic16(u64 v[MAXK]) {
#pragma unroll
    for (int k = 2; k <= 16; k <<= 1) {
#pragma unroll
        for (int j = k >> 1; j > 0; j >>= 1) {
#pragma unroll
            for (int i = 0; i < 16; ++i) {
                const int l = i ^ j;
                if (l > i) {
                    const u64 a = v[i], b = v[l];
                    const bool up = ((i & k) == 0);
                    const bool sw = up ? (a > b) : (a < b);
                    v[i] = sw ? b : a;
                    v[l] = sw ? a : b;
                }
            }
        }
    }
}

__device__ __forceinline__ void merge16(u64 list[MAXK], const u64 br[MAXK]) {
    u64 lo[MAXK];
#pragma unroll
    for (int i = 0; i < 16; ++i) {
        const u64 a = list[i], b = br[15 - i];
        lo[i] = a < b ? a : b;
    }
#pragma unroll
    for (int j = 8; j > 0; j >>= 1) {
#pragma unroll
        for (int i = 0; i < 16; ++i) {
            const int l = i ^ j;
            if (l > i) {
                const u64 a = lo[i], b = lo[l];
                const bool sw = a > b;
                lo[i] = sw ? b : a;
                lo[l] = sw ? a : b;
            }
        }
    }
#pragma unroll
    for (int i = 0; i < 16; ++i) list[i] = lo[i];
}

// floorv: append-filter floor (per-lane); wkey = min(list[15], floorv).
__device__ __forceinline__ void flush_buf(u64 list[MAXK], u64& wkey, int& cnt,
                                          const u64 (*buf)[BQ], int lane, u64 floorv) {
    u64 br[MAXK];
#pragma unroll
    for (int i = 0; i < 16; ++i) {
        const u64 v = buf[i][lane];
        br[i] = (i < cnt) ? v : ~0ull;
    }
    bitonic16(br);
    merge16(list, br);
    const u64 l15 = list[15];
    wkey = l15 < floorv ? l15 : floorv;
    cnt = 0;
}

// k = argmax(kvec)+1 (first index wins), gather preds of selected, mean.
__device__ __forceinline__ void write_mean(const float* __restrict__ pb,
                                           const float* __restrict__ kvec,
                                           const u64 list[MAXK],
                                           float* __restrict__ op) {
    float bv = kvec[0]; int bi = 0;
#pragma unroll
    for (int i = 1; i < MAXK; ++i) { const float v = kvec[i]; if (v > bv) { bv = v; bi = i; } }
    const int k = bi + 1;
    float sx = 0.f, sy = 0.f, sz = 0.f;
#pragma unroll
    for (int s = 0; s < MAXK; ++s) {
        if (s < k) {
            const int j = (int)(u32)list[s];
            sx = __fadd_rn(sx, pb[j * 3 + 0]);
            sy = __fadd_rn(sy, pb[j * 3 + 1]);
            sz = __fadd_rn(sz, pb[j * 3 + 2]);
        }
    }
    const float fk = (float)k;
    op[0] = __fdiv_rn(sx, fk);
    op[1] = __fdiv_rn(sy, fk);
    op[2] = __fdiv_rn(sz, fk);
}

// ---- build kernels ----

__global__ __launch_bounds__(256) void knn_zero(u32* __restrict__ p, int n) {
    const int i = blockIdx.x * 256 + (int)threadIdx.x;
    if (i < n) p[i] = 0u;
}

__global__ __launch_bounds__(256) void knn_build(const float* __restrict__ x,
                                                 u32* __restrict__ hist,
                                                 u32* __restrict__ ids) {
    const int g = blockIdx.x * 256 + (int)threadIdx.x;   // 0 .. BB*NN-1
    const int b = g >> 12;
    const float px = x[(size_t)g * 3 + 0];
    const float py = x[(size_t)g * 3 + 1];
    const float pz = x[(size_t)g * 3 + 2];
    int cx = (int)floorf((px - GORIG) * GINVW); cx = cx < 0 ? 0 : (cx > NC - 1 ? NC - 1 : cx);
    int cy = (int)floorf((py - GORIG) * GINVW); cy = cy < 0 ? 0 : (cy > NC - 1 ? NC - 1 : cy);
    int cz = (int)floorf((pz - GORIG) * GINVW); cz = cz < 0 ? 0 : (cz > NC - 1 ? NC - 1 : cz);
    const u32 m = morton3(cx, cy, cz);
    ids[g] = m;
    atomicAdd(&hist[b * NCM + (int)m], 1u);
}

// Exclusive prefix per batch over morton-ordered cells; desc = (count<<32)|start.
__global__ __launch_bounds__(1024) void knn_prefix(const u32* __restrict__ hist,
                                                   u64* __restrict__ desc,
                                                   u32* __restrict__ cursor) {
    const int b = blockIdx.x;
    const int tid = (int)threadIdx.x;
    const int lane = tid & 63, wid = tid >> 6;
    __shared__ u32 wsum[16];
    u32 carry = 0;
    for (int c0 = 0; c0 < NCM; c0 += 4096) {
        const int base = b * NCM + c0 + tid * 4;
        const uint4 v = *(const uint4*)(hist + base);
        const u32 s0 = v.x, s1 = s0 + v.y, s2 = s1 + v.z, s3 = s2 + v.w;
        u32 inc = s3;
#pragma unroll
        for (int off = 1; off < 64; off <<= 1) {
            const u32 n = __shfl_up(inc, off);
            if (lane >= off) inc += n;
        }
        if (lane == 63) wsum[wid] = inc;
        __syncthreads();
        if (wid == 0) {
            u32 s = (lane < 16) ? wsum[lane] : 0u;
#pragma unroll
            for (int off = 1; off < 16; off <<= 1) {
                const u32 n = __shfl_up(s, off);
                if (lane >= off) s += n;
            }
            if (lane < 16) wsum[lane] = s;
        }
        __syncthreads();
        const u32 woff = wid ? wsum[wid - 1] : 0u;
        const u32 tot = wsum[15];
        const u32 excl = carry + woff + (inc - s3);
        const u32 st0 = excl, st1 = excl + s0, st2 = excl + s1, st3 = excl + s2;
        desc[base + 0] = ((u64)v.x << 32) | st0;
        desc[base + 1] = ((u64)v.y << 32) | st1;
        desc[base + 2] = ((u64)v.z << 32) | st2;
        desc[base + 3] = ((u64)v.w << 32) | st3;
        cursor[base + 0] = st0; cursor[base + 1] = st1;
        cursor[base + 2] = st2; cursor[base + 3] = st3;
        __syncthreads();
        carry += tot;
    }
}

// Scatter into morton-sorted order; payload (2x, 2y, 2z, bitcast(orig idx)).
// sq is recomputed exactly from doubled coords (scaling by 4 commutes with fp
// rounding), so d2 stays bit-identical to the reference.
__global__ __launch_bounds__(256) void knn_scatter(const float* __restrict__ x,
                                                   const u32* __restrict__ ids,
                                                   u32* __restrict__ cursor,
                                                   float4* __restrict__ tab) {
    const int g = blockIdx.x * 256 + (int)threadIdx.x;
    const int b = g >> 12, i = g & (NN - 1);
    const u32 id = ids[g];
    const u32 p = atomicAdd(&cursor[b * NCM + (int)id], 1u);   // batch-local slot
    const float cx = x[(size_t)g * 3 + 0];
    const float cy = x[(size_t)g * 3 + 1];
    const float cz = x[(size_t)g * 3 + 2];
    float4 o;
    o.x = __fadd_rn(cx, cx); o.y = __fadd_rn(cy, cy); o.z = __fadd_rn(cz, cz);
    o.w = __uint_as_float((u32)i);
    tab[(size_t)b * NN + p] = o;
}

// ---- main: per-wave Morton-range stream (R3-style proven loop) ----

// csq4 = fl(fl((2x)^2+(2y)^2)+(2z)^2) = 4*fl(fl(x^2+y^2)+z^2)  (exact scaling)
// inner2 = 2*inner exactly; d2 = fl(fl(qsq+sq) - inner2) == reference bits.
#define STREAM8(SLO, SHI, FLOORV) do {                                        \
    for (int t_ = (SLO); t_ < (SHI); t_ += 8) {                               \
        if (__any((int)(cnt > BUFSLOTS - 8)))                                 \
            flush_buf(list, wkey, cnt, buf, lane, (FLOORV));                  \
        _Pragma("unroll")                                                     \
        for (int u_ = 0; u_ < 8; ++u_) {                                      \
            const int s_ = t_ + u_;                                           \
            if (s_ < (SHI)) {                                                 \
                const float4 c_ = tb[s_];                                     \
                const float sq_ = __fmul_rn(0.25f, __fadd_rn(__fadd_rn(       \
                    __fmul_rn(c_.x, c_.x), __fmul_rn(c_.y, c_.y)),            \
                    __fmul_rn(c_.z, c_.z)));                                  \
                const float in2_ = __fadd_rn(__fadd_rn(                       \
                    __fmul_rn(qx, c_.x), __fmul_rn(qy, c_.y)),                \
                    __fmul_rn(qz, c_.z));                                     \
                float d2_ = __fsub_rn(__fadd_rn(qsq, sq_), in2_);             \
                d2_ = fmaxf(d2_, 0.0f);                                       \
                const u64 key_ = ((u64)__float_as_uint(d2_) << 32)            \
                               | (u64)__float_as_uint(c_.w);                  \
                buf[cnt][lane] = key_;                                        \
                cnt += (key_ < wkey) ? 1 : 0;                                 \
            }                                                                 \
        }                                                                     \
    }                                                                         \
    flush_buf(list, wkey, cnt, buf, lane, (FLOORV));                          \
} while (0)

template <int SIBS>
__global__ __launch_bounds__(BQ) void knn_range(
    const float4* __restrict__ tab, const u64* __restrict__ desc,
    u64* __restrict__ keys)
{
    const int lane = (int)threadIdx.x;
    int bid = blockIdx.x;
    const int sib = bid % SIBS; bid /= SIBS;
    const int b = bid >> 6;
    const int wbegin = (bid & 63) * BQ;              // within-batch sorted slot base
    const float4* tb = tab + (size_t)b * NN;
    const u64* descb = desc + (size_t)b * NCM;

    const float4 qv = tb[wbegin + lane];             // (2x,2y,2z,orig)
    const float qx = __fmul_rn(0.5f, qv.x);          // exact
    const float qy = __fmul_rn(0.5f, qv.y);
    const float qz = __fmul_rn(0.5f, qv.z);
    const float qsq = __fmul_rn(0.25f, __fadd_rn(__fadd_rn(
        __fmul_rn(qv.x, qv.x), __fmul_rn(qv.y, qv.y)), __fmul_rn(qv.z, qv.z)));

    __shared__ u64 buf[BUFSLOTS][BQ];   // [slot][lane] -> 2-way banks (free)

    u64 list[MAXK];
#pragma unroll
    for (int s = 0; s < MAXK; ++s) list[s] = ~0ull;
    u64 wkey = ~0ull;
    int cnt = 0;

    // Phase A: own 64 Morton-adjacent points (includes self, d2==0 exactly).
    // All siblings run it (cheap) purely to establish the per-lane floor.
    STREAM8(wbegin, wbegin + BQ, ~0ull);

    const u64 paw = wkey;            // per-lane 16th-best key over own blob
    const u64 floorv = paw + 1ull;   // strict < then accepts key == paw
#pragma unroll
    for (int s = 0; s < MAXK; ++s) list[s] = ~0ull;   // discard; re-found in stream
    wkey = floorv;
    cnt = 0;

    // Wave bounding box + conservative radius (wave-max 16th d2 + margin).
    float bxlo = qx, bxhi = qx, bylo = qy, byhi = qy, bzlo = qz, bzhi = qz;
    float r2 = __uint_as_float((u32)(paw >> 32));
#pragma unroll
    for (int off = 32; off; off >>= 1) {
        bxlo = fminf(bxlo, __shfl_xor(bxlo, off)); bxhi = fmaxf(bxhi, __shfl_xor(bxhi, off));
        bylo = fminf(bylo, __shfl_xor(bylo, off)); byhi = fmaxf(byhi, __shfl_xor(byhi, off));
        bzlo = fminf(bzlo, __shfl_xor(bzlo, off)); bzhi = fmaxf(bzhi, __shfl_xor(bzhi, off));
        r2 = fmaxf(r2, __shfl_xor(r2, off));
    }
    r2 = __fadd_rn(r2, MARGIN);
    const float r = __fadd_rn(sqrtf(r2), 1.0e-4f);   // ulp slack on sqrt

    int cxlo = (int)floorf((bxlo - r - GORIG) * GINVW);
    int cxhi = (int)floorf((bxhi + r - GORIG) * GINVW);
    int cylo = (int)floorf((bylo - r - GORIG) * GINVW);
    int cyhi = (int)floorf((byhi + r - GORIG) * GINVW);
    int czlo = (int)floorf((bzlo - r - GORIG) * GINVW);
    int czhi = (int)floorf((bzhi + r - GORIG) * GINVW);
    cxlo = cxlo < 0 ? 0 : cxlo; cxhi = cxhi > NC - 1 ? NC - 1 : cxhi;
    cylo = cylo < 0 ? 0 : cylo; cyhi = cyhi > NC - 1 ? NC - 1 : cyhi;
    czlo = czlo < 0 ? 0 : czlo; czhi = czhi > NC - 1 ? NC - 1 : czhi;
    cxlo = __builtin_amdgcn_readfirstlane(cxlo); cxhi = __builtin_amdgcn_readfirstlane(cxhi);
    cylo = __builtin_amdgcn_readfirstlane(cylo); cyhi = __builtin_amdgcn_readfirstlane(cyhi);
    czlo = __builtin_amdgcn_readfirstlane(czlo); czhi = __builtin_amdgcn_readfirstlane(czhi);

    // Morton monotonicity: all cells of the AABB lie in [morton(lo), morton(hi)]
    // -> one contiguous sorted-slot range. Exactly 2 descriptor loads.
    const u64 dlo = descb[morton3(cxlo, cylo, czlo)];
    const u64 dhi = descb[morton3(cxhi, cyhi, czhi)];
    const int rlo = (int)(u32)dlo;
    const int rhi = (int)((u32)dhi + (u32)(dhi >> 32));

    // Disjoint SIBS-way split of the range (covers own slots exactly once).
    const int len = rhi - rlo;
    const int ql = (len + SIBS - 1) / SIBS;
    const int slo = rlo + sib * ql;
    const int shi = (slo + ql < rhi) ? (slo + ql) : rhi;
    if (slo < shi) {
        STREAM8(slo, shi, floorv);
    }

    // Coalesced key dump; merge maps sorted slot -> orig.
    const size_t qs = (size_t)b * NN + wbegin + lane;
#pragma unroll
    for (int s = 0; s < MAXK; ++s)
        keys[(size_t)(sib * MAXK + s) * (BB * NN) + qs] = list[s];
}

template <int SIBS>
__global__ __launch_bounds__(256) void knn_merge(
    const float* __restrict__ preds, const float* __restrict__ kvec,
    const u64* __restrict__ keys, const float4* __restrict__ tab,
    float* __restrict__ out)
{
    const int qs = blockIdx.x * 256 + (int)threadIdx.x;   // sorted slot, 0..B*N-1

    u64 list[MAXK];
#pragma unroll
    for (int s = 0; s < MAXK; ++s)
        list[s] = keys[(size_t)s * (BB * NN) + qs];        // coalesced
#pragma unroll 1
    for (int g = 1; g < SIBS; ++g) {
        u64 br[MAXK];
#pragma unroll
        for (int s = 0; s < MAXK; ++s)
            br[s] = keys[(size_t)(g * MAXK + s) * (BB * NN) + qs];
        merge16(list, br);
    }

    const int b = qs >> 12;
    const int qorig = (int)__float_as_uint(tab[qs].w);
    write_mean(preds + (size_t)b * NN * 3, kvec, list,
               out + ((size_t)b * NN + qorig) * 3);
}

// ---- fallback: fused brute force (no workspace), known-good structure ----
__global__ __launch_bounds__(BQ) void knn_brute(
    const float* __restrict__ x, const float* __restrict__ preds,
    const float* __restrict__ kvec, float* __restrict__ out)
{
    const int lane = (int)threadIdx.x;
    const int qg = blockIdx.x % (NN / BQ);
    const int b  = blockIdx.x / (NN / BQ);
    const int qi = qg * BQ + lane;
    const float* xb = x + (size_t)b * NN * 3;
    const float qx = xb[qi * 3 + 0], qy = xb[qi * 3 + 1], qz = xb[qi * 3 + 2];
    const float qsq = __fadd_rn(__fadd_rn(__fmul_rn(qx, qx), __fmul_rn(qy, qy)),
                                __fmul_rn(qz, qz));
    __shared__ u64 buf[BUFSLOTS][BQ];
    u64 list[MAXK];
#pragma unroll
    for (int s = 0; s < MAXK; ++s) list[s] = ~0ull;
    u64 wkey = ~0ull;
    int cnt = 0;
#pragma unroll 1
    for (int t = 0; t < NN; t += 4) {
        if (__any((int)(cnt > BUFSLOTS - 4))) flush_buf(list, wkey, cnt, buf, lane, ~0ull);
#pragma unroll
        for (int u = 0; u < 4; ++u) {
            const int j = t + u;
            const float cx = xb[j * 3 + 0], cy = xb[j * 3 + 1], cz = xb[j * 3 + 2];
            const float csq = __fadd_rn(__fadd_rn(__fmul_rn(cx, cx), __fmul_rn(cy, cy)),
                                        __fmul_rn(cz, cz));
            const float inner = __fadd_rn(
                __fadd_rn(__fmul_rn(qx, cx), __fmul_rn(qy, cy)), __fmul_rn(qz, cz));
            float d2 = __fsub_rn(__fadd_rn(qsq, csq), __fmul_rn(2.0f, inner));
            d2 = fmaxf(d2, 0.0f);
            const u64 key = ((u64)__float_as_uint(d2) << 32) | (u32)j;
            buf[cnt][lane] = key;
            cnt += (key < wkey) ? 1 : 0;
        }
    }
    flush_buf(list, wkey, cnt, buf, lane, ~0ull);
    write_mean(preds + (size_t)b * NN * 3, kvec, list,
               out + ((size_t)b * NN + qi) * 3);
}

extern "C" void kernel_launch(void* const* d_in, const int* in_sizes, int n_in,
                              void* d_out, int out_size, void* d_ws, size_t ws_size,
                              hipStream_t stream) {
    (void)in_sizes; (void)n_in; (void)out_size;
    const float* x     = (const float*)d_in[0];
    const float* preds = (const float*)d_in[1];
    const float* kvec  = (const float*)d_in[2];
    float* out = (float*)d_out;

    // ws layout sized by SIBS: TAB | KEYS | DESC | HIST | CUR | IDS
    const size_t tab_b  = (size_t)BB * NN * 16;
    const size_t desc_b = (size_t)BB * NCM * 8;
    const size_t hist_b = (size_t)BB * NCM * 4;
    const size_t ids_b  = (size_t)BB * NN * 4;
    auto need = [&](int sibs) {
        return tab_b + (size_t)sibs * MAXK * BB * NN * 8 + desc_b + 2 * hist_b + ids_b;
    };

    int sibs = 0;
    if      (ws_size >= need(8)) sibs = 8;
    else if (ws_size >= need(4)) sibs = 4;

    if (sibs) {
        char* w = (char*)d_ws;
        const size_t keys_b = (size_t)sibs * MAXK * BB * NN * 8;
        float4* tab  = (float4*)w;
        u64* keys    = (u64*)(w + tab_b);
        u64* descp   = (u64*)(w + tab_b + keys_b);
        u32* hist    = (u32*)(w + tab_b + keys_b + desc_b);
        u32* cursor  = (u32*)(w + tab_b + keys_b + desc_b + hist_b);
        u32* ids     = (u32*)(w + tab_b + keys_b + desc_b + 2 * hist_b);

        knn_zero<<<(BB * NCM) / 256, 256, 0, stream>>>(hist, BB * NCM);
        knn_build<<<(BB * NN) / 256, 256, 0, stream>>>(x, hist, ids);
        knn_prefix<<<BB, 1024, 0, stream>>>(hist, descp, cursor);
        knn_scatter<<<(BB * NN) / 256, 256, 0, stream>>>(x, ids, cursor, tab);
        if (sibs == 8) {
            knn_range<8><<<BB * (NN / BQ) * 8, BQ, 0, stream>>>(tab, descp, keys);
            knn_merge<8><<<(BB * NN) / 256, 256, 0, stream>>>(preds, kvec, keys, tab, out);
        } else {
            knn_range<4><<<BB * (NN / BQ) * 4, BQ, 0, stream>>>(tab, descp, keys);
            knn_merge<4><<<(BB * NN) / 256, 256, 0, stream>>>(preds, kvec, keys, tab, out);
        }
    } else {
        knn_brute<<<BB * (NN / BQ), BQ, 0, stream>>>(x, preds, kvec, out);
    }
}

// Round 10
// 272.894 us; speedup vs baseline: 4.9562x; 1.0598x over previous
//
#include <hip/hip_runtime.h>
#include <math.h>

typedef unsigned long long u64;
typedef unsigned int u32;

#define BB 8
#define NN 4096
#define MAXK 16
#define BQ 64          // one wave per block
#define BUFSLOTS 16    // per-lane LDS append buffer (8 KB/block)

// spatial grid: 32^3, centered so the Gaussian mean sits on the top Morton
// boundary (cell 16) -> octant-split intervals stay tight at the center.
#define NC 32
#define NCH 16
#define NCM (1 << 15)
#define GW 0.28f
#define GORIG (-4.48f)
#define GINVW (1.0f / GW)
// Pruning margin: covers |d2_fp - d2_true| (<= ~3e-5) with large slack.
#define MARGIN 2.0e-3f

__device__ __forceinline__ u32 part1by2(u32 x) {
    x &= 0x3FF;
    x = (x | (x << 16)) & 0x030000FF;
    x = (x | (x << 8))  & 0x0300F00F;
    x = (x | (x << 4))  & 0x030C30C3;
    x = (x | (x << 2))  & 0x09249249;
    return x;
}
__device__ __forceinline__ u32 morton3(int cx, int cy, int cz) {
    return (part1by2((u32)cz) << 2) | (part1by2((u32)cy) << 1) | part1by2((u32)cx);
}

// ---- branch-free in-register top-16 machinery (u64 keys, ascending) ----

__device__ __forceinline__ void bitonic16(u64 v[MAXK]) {
#pragma unroll
    for (int k = 2; k <= 16; k <<= 1) {
#pragma unroll
        for (int j = k >> 1; j > 0; j >>= 1) {
#pragma unroll
            for (int i = 0; i < 16; ++i) {
                const int l = i ^ j;
                if (l > i) {
                    const u64 a = v[i], b = v[l];
                    const bool up = ((i & k) == 0);
                    const bool sw = up ? (a > b) : (a < b);
                    v[i] = sw ? b : a;
                    v[l] = sw ? a : b;
                }
            }
        }
    }
}

__device__ __forceinline__ void merge16(u64 list[MAXK], const u64 br[MAXK]) {
    u64 lo[MAXK];
#pragma unroll
    for (int i = 0; i < 16; ++i) {
        const u64 a = list[i], b = br[15 - i];
        lo[i] = a < b ? a : b;
    }
#pragma unroll
    for (int j = 8; j > 0; j >>= 1) {
#pragma unroll
        for (int i = 0; i < 16; ++i) {
            const int l = i ^ j;
            if (l > i) {
                const u64 a = lo[i], b = lo[l];
                const bool sw = a > b;
                lo[i] = sw ? b : a;
                lo[l] = sw ? a : b;
            }
        }
    }
#pragma unroll
    for (int i = 0; i < 16; ++i) list[i] = lo[i];
}

// floorv: append-filter floor (per-lane); wkey = min(list[15], floorv).
__device__ __forceinline__ void flush_buf(u64 list[MAXK], u64& wkey, int& cnt,
                                          const u64 (*buf)[BQ], int lane, u64 floorv) {
    u64 br[MAXK];
#pragma unroll
    for (int i = 0; i < 16; ++i) {
        const u64 v = buf[i][lane];
        br[i] = (i < cnt) ? v : ~0ull;
    }
    bitonic16(br);
    merge16(list, br);
    const u64 l15 = list[15];
    wkey = l15 < floorv ? l15 : floorv;
    cnt = 0;
}

// k = argmax(kvec)+1 (first index wins), gather preds of selected, mean.
__device__ __forceinline__ void write_mean(const float* __restrict__ pb,
                                           const float* __restrict__ kvec,
                                           const u64 list[MAXK],
                                           float* __restrict__ op) {
    float bv = kvec[0]; int bi = 0;
#pragma unroll
    for (int i = 1; i < MAXK; ++i) { const float v = kvec[i]; if (v > bv) { bv = v; bi = i; } }
    const int k = bi + 1;
    float sx = 0.f, sy = 0.f, sz = 0.f;
#pragma unroll
    for (int s = 0; s < MAXK; ++s) {
        if (s < k) {
            const int j = (int)(u32)list[s];
            sx = __fadd_rn(sx, pb[j * 3 + 0]);
            sy = __fadd_rn(sy, pb[j * 3 + 1]);
            sz = __fadd_rn(sz, pb[j * 3 + 2]);
        }
    }
    const float fk = (float)k;
    op[0] = __fdiv_rn(sx, fk);
    op[1] = __fdiv_rn(sy, fk);
    op[2] = __fdiv_rn(sz, fk);
}

// ---- build kernels ----

__global__ __launch_bounds__(256) void knn_zero(u32* __restrict__ p, int n) {
    const int i = blockIdx.x * 256 + (int)threadIdx.x;
    if (i < n) p[i] = 0u;
}

__global__ __launch_bounds__(256) void knn_build(const float* __restrict__ x,
                                                 u32* __restrict__ hist,
                                                 u32* __restrict__ ids) {
    const int g = blockIdx.x * 256 + (int)threadIdx.x;   // 0 .. BB*NN-1
    const int b = g >> 12;
    const float px = x[(size_t)g * 3 + 0];
    const float py = x[(size_t)g * 3 + 1];
    const float pz = x[(size_t)g * 3 + 2];
    int cx = (int)floorf((px - GORIG) * GINVW); cx = cx < 0 ? 0 : (cx > NC - 1 ? NC - 1 : cx);
    int cy = (int)floorf((py - GORIG) * GINVW); cy = cy < 0 ? 0 : (cy > NC - 1 ? NC - 1 : cy);
    int cz = (int)floorf((pz - GORIG) * GINVW); cz = cz < 0 ? 0 : (cz > NC - 1 ? NC - 1 : cz);
    const u32 m = morton3(cx, cy, cz);
    ids[g] = m;
    atomicAdd(&hist[b * NCM + (int)m], 1u);
}

// Exclusive prefix per batch over morton-ordered cells; desc = (count<<32)|start.
__global__ __launch_bounds__(1024) void knn_prefix(const u32* __restrict__ hist,
                                                   u64* __restrict__ desc,
                                                   u32* __restrict__ cursor) {
    const int b = blockIdx.x;
    const int tid = (int)threadIdx.x;
    const int lane = tid & 63, wid = tid >> 6;
    __shared__ u32 wsum[16];
    u32 carry = 0;
    for (int c0 = 0; c0 < NCM; c0 += 4096) {
        const int base = b * NCM + c0 + tid * 4;
        const uint4 v = *(const uint4*)(hist + base);
        const u32 s0 = v.x, s1 = s0 + v.y, s2 = s1 + v.z, s3 = s2 + v.w;
        u32 inc = s3;
#pragma unroll
        for (int off = 1; off < 64; off <<= 1) {
            const u32 n = __shfl_up(inc, off);
            if (lane >= off) inc += n;
        }
        if (lane == 63) wsum[wid] = inc;
        __syncthreads();
        if (wid == 0) {
            u32 s = (lane < 16) ? wsum[lane] : 0u;
#pragma unroll
            for (int off = 1; off < 16; off <<= 1) {
                const u32 n = __shfl_up(s, off);
                if (lane >= off) s += n;
            }
            if (lane < 16) wsum[lane] = s;
        }
        __syncthreads();
        const u32 woff = wid ? wsum[wid - 1] : 0u;
        const u32 tot = wsum[15];
        const u32 excl = carry + woff + (inc - s3);
        const u32 st0 = excl, st1 = excl + s0, st2 = excl + s1, st3 = excl + s2;
        desc[base + 0] = ((u64)v.x << 32) | st0;
        desc[base + 1] = ((u64)v.y << 32) | st1;
        desc[base + 2] = ((u64)v.z << 32) | st2;
        desc[base + 3] = ((u64)v.w << 32) | st3;
        cursor[base + 0] = st0; cursor[base + 1] = st1;
        cursor[base + 2] = st2; cursor[base + 3] = st3;
        __syncthreads();
        carry += tot;
    }
}

// Scatter into morton-sorted order; payload (2x,2y,2z,sq) + orig idx.
__global__ __launch_bounds__(256) void knn_scatter(const float* __restrict__ x,
                                                   const u32* __restrict__ ids,
                                                   u32* __restrict__ cursor,
                                                   float4* __restrict__ tab,
                                                   u32* __restrict__ sorg) {
    const int g = blockIdx.x * 256 + (int)threadIdx.x;
    const int b = g >> 12, i = g & (NN - 1);
    const u32 id = ids[g];
    const u32 p = atomicAdd(&cursor[b * NCM + (int)id], 1u);   // batch-local slot
    const float cx = x[(size_t)g * 3 + 0];
    const float cy = x[(size_t)g * 3 + 1];
    const float cz = x[(size_t)g * 3 + 2];
    const float sq = __fadd_rn(__fadd_rn(__fmul_rn(cx, cx), __fmul_rn(cy, cy)),
                               __fmul_rn(cz, cz));
    tab[(size_t)b * NN + p] = make_float4(__fadd_rn(cx, cx), __fadd_rn(cy, cy),
                                          __fadd_rn(cz, cz), sq);
    sorg[(size_t)b * NN + p] = (u32)i;
}

// ---- main: per-wave octant-split Morton-range stream ----

// inner2 == 2*inner exactly (doubled coords); d2 bit-identical to reference.
#define STREAM8(SLO, SHI, FLOORV) do {                                        \
    for (int t_ = (SLO); t_ < (SHI); t_ += 8) {                               \
        if (__any((int)(cnt > BUFSLOTS - 8)))                                 \
            flush_buf(list, wkey, cnt, buf, lane, (FLOORV));                  \
        _Pragma("unroll")                                                     \
        for (int u_ = 0; u_ < 8; ++u_) {                                      \
            const int s_ = t_ + u_;                                           \
            if (s_ < (SHI)) {                                                 \
                const float4 c_ = tb[s_];                                     \
                const u32 co_ = sg[s_];                                       \
                const float in2_ = __fadd_rn(__fadd_rn(                       \
                    __fmul_rn(qx, c_.x), __fmul_rn(qy, c_.y)),                \
                    __fmul_rn(qz, c_.z));                                     \
                float d2_ = __fsub_rn(__fadd_rn(qsq, c_.w), in2_);            \
                d2_ = fmaxf(d2_, 0.0f);                                       \
                const u64 key_ = ((u64)__float_as_uint(d2_) << 32)            \
                               | (u64)co_;                                    \
                buf[cnt][lane] = key_;                                        \
                cnt += (key_ < wkey) ? 1 : 0;                                 \
            }                                                                 \
        }                                                                     \
    }                                                                         \
    flush_buf(list, wkey, cnt, buf, lane, (FLOORV));                          \
} while (0)

template <int SIBS>
__global__ __launch_bounds__(BQ) void knn_range(
    const float4* __restrict__ tab, const u32* __restrict__ sorg,
    const u64* __restrict__ desc, u64* __restrict__ keys)
{
    const int lane = (int)threadIdx.x;
    int bid = blockIdx.x;
    const int sib = bid % SIBS; bid /= SIBS;
    const int b = bid >> 6;
    const int wbegin = (bid & 63) * BQ;              // within-batch sorted slot base
    const float4* tb = tab + (size_t)b * NN;
    const u32* sg = sorg + (size_t)b * NN;
    const u64* descb = desc + (size_t)b * NCM;

    const float4 qv = tb[wbegin + lane];             // (2x,2y,2z,sq)
    const float qx = __fmul_rn(0.5f, qv.x);          // exact
    const float qy = __fmul_rn(0.5f, qv.y);
    const float qz = __fmul_rn(0.5f, qv.z);
    const float qsq = qv.w;

    __shared__ u64 buf[BUFSLOTS][BQ];   // [slot][lane] -> 2-way banks (free)

    u64 list[MAXK];
#pragma unroll
    for (int s = 0; s < MAXK; ++s) list[s] = ~0ull;
    u64 wkey = ~0ull;
    int cnt = 0;

    // Phase A: own 64 Morton-adjacent points, purely to establish the floor.
    // Step-16 batches with cnt>0 trigger: exactly 4 flushes (all lanes append).
#pragma unroll 1
    for (int t = 0; t < BQ; t += 16) {
        if (__any((int)(cnt > 0)))
            flush_buf(list, wkey, cnt, buf, lane, ~0ull);
#pragma unroll
        for (int u = 0; u < 16; ++u) {
            const int s_ = wbegin + t + u;
            const float4 c_ = tb[s_];
            const u32 co_ = sg[s_];
            const float in2_ = __fadd_rn(__fadd_rn(
                __fmul_rn(qx, c_.x), __fmul_rn(qy, c_.y)), __fmul_rn(qz, c_.z));
            float d2_ = __fsub_rn(__fadd_rn(qsq, c_.w), in2_);
            d2_ = fmaxf(d2_, 0.0f);
            const u64 key_ = ((u64)__float_as_uint(d2_) << 32) | (u64)co_;
            buf[cnt][lane] = key_;
            cnt += (key_ < wkey) ? 1 : 0;
        }
    }
    flush_buf(list, wkey, cnt, buf, lane, ~0ull);

    const u64 paw = wkey;            // per-lane 16th-best key over own blob
    const u64 floorv = paw + 1ull;   // strict < then accepts key == paw
#pragma unroll
    for (int s = 0; s < MAXK; ++s) list[s] = ~0ull;   // discard; re-found in stream
    wkey = floorv;
    cnt = 0;

    // Wave bounding box + conservative radius (wave-max 16th d2 + margin).
    float bxlo = qx, bxhi = qx, bylo = qy, byhi = qy, bzlo = qz, bzhi = qz;
    float r2 = __uint_as_float((u32)(paw >> 32));
#pragma unroll
    for (int off = 32; off; off >>= 1) {
        bxlo = fminf(bxlo, __shfl_xor(bxlo, off)); bxhi = fmaxf(bxhi, __shfl_xor(bxhi, off));
        bylo = fminf(bylo, __shfl_xor(bylo, off)); byhi = fmaxf(byhi, __shfl_xor(byhi, off));
        bzlo = fminf(bzlo, __shfl_xor(bzlo, off)); bzhi = fmaxf(bzhi, __shfl_xor(bzhi, off));
        r2 = fmaxf(r2, __shfl_xor(r2, off));
    }
    r2 = __fadd_rn(r2, MARGIN);
    const float r = __fadd_rn(sqrtf(r2), 1.0e-4f);   // ulp slack on sqrt

    int cxlo = (int)floorf((bxlo - r - GORIG) * GINVW);
    int cxhi = (int)floorf((bxhi + r - GORIG) * GINVW);
    int cylo = (int)floorf((bylo - r - GORIG) * GINVW);
    int cyhi = (int)floorf((byhi + r - GORIG) * GINVW);
    int czlo = (int)floorf((bzlo - r - GORIG) * GINVW);
    int czhi = (int)floorf((bzhi + r - GORIG) * GINVW);
    cxlo = cxlo < 0 ? 0 : cxlo; cxhi = cxhi > NC - 1 ? NC - 1 : cxhi;
    cylo = cylo < 0 ? 0 : cylo; cyhi = cyhi > NC - 1 ? NC - 1 : cyhi;
    czlo = czlo < 0 ? 0 : czlo; czhi = czhi > NC - 1 ? NC - 1 : czhi;
    cxlo = __builtin_amdgcn_readfirstlane(cxlo); cxhi = __builtin_amdgcn_readfirstlane(cxhi);
    cylo = __builtin_amdgcn_readfirstlane(cylo); cyhi = __builtin_amdgcn_readfirstlane(cyhi);
    czlo = __builtin_amdgcn_readfirstlane(czlo); czhi = __builtin_amdgcn_readfirstlane(czhi);

    // Octant split at the center planes (cell NCH): each sub-box's cells share
    // the per-axis top bit -> tight contiguous Morton interval per octant.
    // Sub-boxes disjoint; intervals in distinct octants disjoint -> no
    // candidate streamed twice. Overscan inside an interval is filtered by
    // the exact key test; box cells are all covered (union = box).
#pragma unroll 1
    for (int oz = 0; oz < 2; ++oz) {
        const int szlo = oz ? (czlo > NCH ? czlo : NCH) : czlo;
        const int szhi = oz ? czhi : (czhi < NCH - 1 ? czhi : NCH - 1);
        if (szlo > szhi) continue;
#pragma unroll 1
        for (int oy = 0; oy < 2; ++oy) {
            const int sylo = oy ? (cylo > NCH ? cylo : NCH) : cylo;
            const int syhi = oy ? cyhi : (cyhi < NCH - 1 ? cyhi : NCH - 1);
            if (sylo > syhi) continue;
#pragma unroll 1
            for (int ox = 0; ox < 2; ++ox) {
                const int sxlo = ox ? (cxlo > NCH ? cxlo : NCH) : cxlo;
                const int sxhi = ox ? cxhi : (cxhi < NCH - 1 ? cxhi : NCH - 1);
                if (sxlo > sxhi) continue;
                const u64 dlo = descb[morton3(sxlo, sylo, szlo)];
                const u64 dhi = descb[morton3(sxhi, syhi, szhi)];
                const int rlo = (int)(u32)dlo;
                const int rhi = (int)((u32)dhi + (u32)(dhi >> 32));
                const int len = rhi - rlo;
                if (len <= 0) continue;
                const int ql = (len + SIBS - 1) / SIBS;
                const int slo = rlo + sib * ql;
                const int shi = (slo + ql < rhi) ? (slo + ql) : rhi;
                if (slo < shi) {
                    STREAM8(slo, shi, floorv);
                }
            }
        }
    }

    // Coalesced key dump; merge maps sorted slot -> orig.
    const size_t qs = (size_t)b * NN + wbegin + lane;
#pragma unroll
    for (int s = 0; s < MAXK; ++s)
        keys[(size_t)(sib * MAXK + s) * (BB * NN) + qs] = list[s];
}

template <int SIBS>
__global__ __launch_bounds__(256) void knn_merge(
    const float* __restrict__ preds, const float* __restrict__ kvec,
    const u64* __restrict__ keys, const u32* __restrict__ sorg,
    float* __restrict__ out)
{
    const int qs = blockIdx.x * 256 + (int)threadIdx.x;   // sorted slot, 0..B*N-1

    u64 list[MAXK];
#pragma unroll
    for (int s = 0; s < MAXK; ++s)
        list[s] = keys[(size_t)s * (BB * NN) + qs];        // coalesced
#pragma unroll 1
    for (int g = 1; g < SIBS; ++g) {
        u64 br[MAXK];
#pragma unroll
        for (int s = 0; s < MAXK; ++s)
            br[s] = keys[(size_t)(g * MAXK + s) * (BB * NN) + qs];
        merge16(list, br);
    }

    const int b = qs >> 12;
    const int qorig = (int)sorg[qs];
    write_mean(preds + (size_t)b * NN * 3, kvec, list,
               out + ((size_t)b * NN + qorig) * 3);
}

// ---- fallback: fused brute force (no workspace), known-good structure ----
__global__ __launch_bounds__(BQ) void knn_brute(
    const float* __restrict__ x, const float* __restrict__ preds,
    const float* __restrict__ kvec, float* __restrict__ out)
{
    const int lane = (int)threadIdx.x;
    const int qg = blockIdx.x % (NN / BQ);
    const int b  = blockIdx.x / (NN / BQ);
    const int qi = qg * BQ + lane;
    const float* xb = x + (size_t)b * NN * 3;
    const float qx = xb[qi * 3 + 0], qy = xb[qi * 3 + 1], qz = xb[qi * 3 + 2];
    const float qsq = __fadd_rn(__fadd_rn(__fmul_rn(qx, qx), __fmul_rn(qy, qy)),
                                __fmul_rn(qz, qz));
    __shared__ u64 buf[BUFSLOTS][BQ];
    u64 list[MAXK];
#pragma unroll
    for (int s = 0; s < MAXK; ++s) list[s] = ~0ull;
    u64 wkey = ~0ull;
    int cnt = 0;
#pragma unroll 1
    for (int t = 0; t < NN; t += 4) {
        if (__any((int)(cnt > BUFSLOTS - 4))) flush_buf(list, wkey, cnt, buf, lane, ~0ull);
#pragma unroll
        for (int u = 0; u < 4; ++u) {
            const int j = t + u;
            const float cx = xb[j * 3 + 0], cy = xb[j * 3 + 1], cz = xb[j * 3 + 2];
            const float csq = __fadd_rn(__fadd_rn(__fmul_rn(cx, cx), __fmul_rn(cy, cy)),
                                        __fmul_rn(cz, cz));
            const float inner = __fadd_rn(
                __fadd_rn(__fmul_rn(qx, cx), __fmul_rn(qy, cy)), __fmul_rn(qz, cz));
            float d2 = __fsub_rn(__fadd_rn(qsq, csq), __fmul_rn(2.0f, inner));
            d2 = fmaxf(d2, 0.0f);
            const u64 key = ((u64)__float_as_uint(d2) << 32) | (u32)j;
            buf[cnt][lane] = key;
            cnt += (key < wkey) ? 1 : 0;
        }
    }
    flush_buf(list, wkey, cnt, buf, lane, ~0ull);
    write_mean(preds + (size_t)b * NN * 3, kvec, list,
               out + ((size_t)b * NN + qi) * 3);
}

extern "C" void kernel_launch(void* const* d_in, const int* in_sizes, int n_in,
                              void* d_out, int out_size, void* d_ws, size_t ws_size,
                              hipStream_t stream) {
    (void)in_sizes; (void)n_in; (void)out_size;
    const float* x     = (const float*)d_in[0];
    const float* preds = (const float*)d_in[1];
    const float* kvec  = (const float*)d_in[2];
    float* out = (float*)d_out;

    // ws layout sized by SIBS: TAB | KEYS | DESC | HIST | CUR | IDS | SORG
    const size_t tab_b  = (size_t)BB * NN * 16;
    const size_t desc_b = (size_t)BB * NCM * 8;
    const size_t hist_b = (size_t)BB * NCM * 4;
    const size_t ids_b  = (size_t)BB * NN * 4;
    auto need = [&](int sibs) {
        return tab_b + (size_t)sibs * MAXK * BB * NN * 8 + desc_b + 2 * hist_b
             + 2 * ids_b;
    };

    int sibs = 0;
    if      (ws_size >= need(8)) sibs = 8;
    else if (ws_size >= need(4)) sibs = 4;

    if (sibs) {
        char* w = (char*)d_ws;
        const size_t keys_b = (size_t)sibs * MAXK * BB * NN * 8;
        float4* tab  = (float4*)w;
        u64* keys    = (u64*)(w + tab_b);
        u64* descp   = (u64*)(w + tab_b + keys_b);
        u32* hist    = (u32*)(w + tab_b + keys_b + desc_b);
        u32* cursor  = (u32*)(w + tab_b + keys_b + desc_b + hist_b);
        u32* ids     = (u32*)(w + tab_b + keys_b + desc_b + 2 * hist_b);
        u32* sorg    = (u32*)(w + tab_b + keys_b + desc_b + 2 * hist_b + ids_b);

        knn_zero<<<(BB * NCM) / 256, 256, 0, stream>>>(hist, BB * NCM);
        knn_build<<<(BB * NN) / 256, 256, 0, stream>>>(x, hist, ids);
        knn_prefix<<<BB, 1024, 0, stream>>>(hist, descp, cursor);
        knn_scatter<<<(BB * NN) / 256, 256, 0, stream>>>(x, ids, cursor, tab, sorg);
        if (sibs == 8) {
            knn_range<8><<<BB * (NN / BQ) * 8, BQ, 0, stream>>>(tab, sorg, descp, keys);
            knn_merge<8><<<(BB * NN) / 256, 256, 0, stream>>>(preds, kvec, keys, sorg, out);
        } else {
            knn_range<4><<<BB * (NN / BQ) * 4, BQ, 0, stream>>>(tab, sorg, descp, keys);
            knn_merge<4><<<(BB * NN) / 256, 256, 0, stream>>>(preds, kvec, keys, sorg, out);
        }
    } else {
        knn_brute<<<BB * (NN / BQ), BQ, 0, stream>>>(x, preds, kvec, out);
    }
}